// Round 19
// baseline (115.026 us; speedup 1.0000x reference)
//
#include <hip/hip_runtime.h>
#include <hip/hip_bf16.h>

typedef __bf16 bf16_t;
typedef __bf16 bf16x2 __attribute__((ext_vector_type(2)));
typedef __bf16 bf16x4 __attribute__((ext_vector_type(4)));
typedef __bf16 bf16x8 __attribute__((ext_vector_type(8)));
typedef float  f32x4  __attribute__((ext_vector_type(4)));

#define DIM     1024
#define NHEAD   16
#define HDIM    64
#define NTIME   4
#define TSEQ    2048
#define NBATCH  2
#define SCALE_F 0.125f          // 64^-0.5
#define LOG2E   1.4426950408889634f

// async global->LDS, 16B per lane; LDS dest = wave-uniform base, HW adds lane*16
#define GLL(gp, lp) __builtin_amdgcn_global_load_lds( \
    (const __attribute__((address_space(1))) unsigned int*)(const void*)(gp), \
    (__attribute__((address_space(3))) unsigned int*)(void*)(lp), 16, 0, 0)

// ---------------- workspace layout (bytes) ----------------
#define OFF_WQKVT 0UL                                   // [3072][1024] bf16 (B^T; cols: Q,K,V)
#define OFF_WOUTT (OFF_WQKVT + 3072UL*1024UL*2UL)       // [1024][1024] bf16 (B^T of Wout)
#define OFF_Q     (OFF_WOUTT + 1024UL*1024UL*2UL)       // [B][NH][T][HD] bf16
#define OFF_K     (OFF_Q  + 2UL*16UL*2048UL*64UL*2UL)   // [B][NH][T][HD] bf16
#define OFF_VT    (OFF_K  + 2UL*16UL*2048UL*64UL*2UL)   // [B][NH][HD][T] bf16 (V^T, sigma-permuted per 32-token block)
#define OFF_CTX   (OFF_VT + 2UL*16UL*2048UL*64UL*2UL)   // [4096][1024] bf16 (Xb before attn; final ctx)

// ---------------- fused prep: x->bf16, Wqkv^T, Wout^T in ONE launch ----------------
__global__ void prep_all(const float* __restrict__ x,
                         const float* __restrict__ Wqt, const float* __restrict__ Wkt,
                         const float* __restrict__ Wqs, const float* __restrict__ Wks,
                         const float* __restrict__ Wv,  const float* __restrict__ Wout,
                         bf16_t* __restrict__ Xb, bf16_t* __restrict__ WqkvT,
                         bf16_t* __restrict__ WoutT) {
    __shared__ float T[64][65];
    const int bid = blockIdx.x;
    if (bid < 2048) {
        int i = bid * 256 + threadIdx.x;
        const float4* s = (const float4*)(x + (size_t)i * 8);
        float4 a = s[0], b2 = s[1];
        bf16x8 v;
        v[0] = (bf16_t)a.x;  v[1] = (bf16_t)a.y;  v[2] = (bf16_t)a.z;  v[3] = (bf16_t)a.w;
        v[4] = (bf16_t)b2.x; v[5] = (bf16_t)b2.y; v[6] = (bf16_t)b2.z; v[7] = (bf16_t)b2.w;
        *(bf16x8*)(Xb + (size_t)i * 8) = v;
        return;
    }
    const int tc = threadIdx.x & 63, tr = threadIdx.x >> 6;   // load partition
    const int sc = threadIdx.x & 31, sr = threadIdx.x >> 5;   // store partition (2 cols/lane)
    if (bid < 2816) {
        const int l = bid - 2048;               // 0..767 = 48 x 16
        const int n0 = (l % 48) * 64;
        const int k0 = (l / 48) * 64;
        const int region = n0 >> 10;
        const int cc = n0 & 1023;
        const int h = cc >> 6;
        const float* src; int ncols, col0;
        if (region == 2) { src = Wv; ncols = 1024; col0 = cc; }
        else if (h < NTIME) { src = (region == 0) ? Wqt : Wkt; ncols = NTIME * HDIM; col0 = h * HDIM; }
        else                { src = (region == 0) ? Wqs : Wks; ncols = (NHEAD - NTIME) * HDIM; col0 = (h - NTIME) * HDIM; }
#pragma unroll
        for (int i = 0; i < 16; ++i) {
            int kl = tr * 16 + i;
            T[kl][tc] = src[(size_t)(k0 + kl) * ncols + col0 + tc];
        }
        __syncthreads();
#pragma unroll
        for (int i = 0; i < 8; ++i) {
            int nl = sr * 8 + i;
            bf16x2 w;
            w[0] = (bf16_t)T[sc * 2][nl];
            w[1] = (bf16_t)T[sc * 2 + 1][nl];
            *(bf16x2*)(WqkvT + (size_t)(n0 + nl) * 1024 + k0 + sc * 2) = w;
        }
    } else {
        const int l = bid - 2816;               // 0..255 = 16 x 16
        const int n0 = (l % 16) * 64;
        const int k0 = (l / 16) * 64;
#pragma unroll
        for (int i = 0; i < 16; ++i) {
            int kl = tr * 16 + i;
            T[kl][tc] = Wout[(size_t)(k0 + kl) * 1024 + n0 + tc];
        }
        __syncthreads();
#pragma unroll
        for (int i = 0; i < 8; ++i) {
            int nl = sr * 8 + i;
            bf16x2 w;
            w[0] = (bf16_t)T[sc * 2][nl];
            w[1] = (bf16_t)T[sc * 2 + 1][nl];
            *(bf16x2*)(WoutT + (size_t)(n0 + nl) * 1024 + k0 + sc * 2) = w;
        }
    }
}

// ---------------- GEMM1: 256x256 tile, BK=64, 8 waves, phased schedule ----------------
// 192 blocks (16m x 12n, XCD-chunked). Per iter (one K-tile): vmcnt(0)+raw barrier
// certifies tile t (cover = 4 phases); 4 phases each {p0: burst-stage tile t+1 into
// other buffer + read 8 bfr; all p: read 4 afr; lgkmcnt(0)+sched_barrier (rule 18);
// setprio(1); 16 MFMA; setprio(0); s_barrier}. Phase barriers keep waves interleaved
// (T3 anti-convoy); counted-wait keeps stages in flight across barriers (T4).
// WAR: iter t+1 stages into cur, whose readers (iter t phases) drained lgkm before
// passing iter t+1's top barrier. Epilogue scatters Q/K (row-major bf16x4) and V
// (transposed + sigma-permuted) exactly like the proven 128^2 kernel.
__global__ __launch_bounds__(512, 2)
void gemm1_8ph(const bf16_t* __restrict__ Ab, const bf16_t* __restrict__ Bt,
               bf16_t* __restrict__ Qb, bf16_t* __restrict__ Kb, bf16_t* __restrict__ Vt)
{
    __shared__ __align__(16) bf16_t As[2][256][64];   // 64 KB: [m][k], rows 128B, chunk^(row&7)
    __shared__ __align__(16) bf16_t Bs[2][256][64];   // 64 KB: [n][k], same swizzle

    const int l  = (blockIdx.x & 7) * 24 + (blockIdx.x >> 3);   // bijective XCD chunk (192%8==0)
    const int m0 = (l / 12) * 256;
    const int n0 = (l % 12) * 256;

    const int tid  = threadIdx.x;          // 0..511
    const int lane = tid & 63;
    const int wave = tid >> 6;             // 0..7
    const int wm = (wave >> 2) * 128;      // 2 m-groups of 128
    const int wn = (wave & 3) * 64;        // 4 n-groups of 64
    const int g = lane >> 4, lr = lane & 15;

    f32x4 acc[8][4];
#pragma unroll
    for (int i = 0; i < 8; ++i)
#pragma unroll
        for (int j = 0; j < 4; ++j) acc[i][j] = f32x4{0.f, 0.f, 0.f, 0.f};

    const int srow = tid >> 3;             // staging: 0..63
    const int scg  = tid & 7;

    // one K-tile = A(256x64) + B(256x64) = 8 GLL/thread
    auto stageTile = [&](int k0, int buf) {
#pragma unroll
        for (int hf = 0; hf < 2; ++hf) {
#pragma unroll
            for (int j = 0; j < 2; ++j) {
                int row = hf * 128 + j * 64 + srow;
                GLL(Ab + (size_t)(m0 + row) * 1024 + k0 + ((scg ^ (row & 7)) << 3),
                    (char*)&As[buf][0][0] + hf * 16384 + j * 8192 + wave * 1024);
                GLL(Bt + (size_t)(n0 + row) * 1024 + k0 + ((scg ^ (row & 7)) << 3),
                    (char*)&Bs[buf][0][0] + hf * 16384 + j * 8192 + wave * 1024);
            }
        }
    };

    stageTile(0, 0);    // prologue (one cold stall at t=0 only)

    for (int t = 0; t < 16; ++t) {
        const int cur = t & 1;
        // own vmcnt(0) retires own GLLs of tile t (cover = previous iter's 4 phases);
        // barrier publishes all threads' contributions (round-14-proven pattern).
        asm volatile("s_waitcnt vmcnt(0)" ::: "memory");
        __builtin_amdgcn_s_barrier();
        __builtin_amdgcn_sched_barrier(0);

        const char* Ac = (const char*)&As[cur][0][0];
        const char* Bc = (const char*)&Bs[cur][0][0];

        bf16x8 bfr[4][2];
#pragma unroll
        for (int p = 0; p < 4; ++p) {
            if (p == 0) {
                if (t + 1 < 16) stageTile((t + 1) * 64, cur ^ 1);
#pragma unroll
                for (int n = 0; n < 4; ++n) {
                    int rb = wn + n * 16 + lr;
#pragma unroll
                    for (int kk = 0; kk < 2; ++kk)
                        bfr[n][kk] = *(const bf16x8*)(Bc + rb * 128 + (((kk * 4 + g) ^ (rb & 7)) << 4));
                }
            }
            bf16x8 afr[2][2];
#pragma unroll
            for (int d = 0; d < 2; ++d) {
                int ra = wm + (2 * p + d) * 16 + lr;
#pragma unroll
                for (int kk = 0; kk < 2; ++kk)
                    afr[d][kk] = *(const bf16x8*)(Ac + ra * 128 + (((kk * 4 + g) ^ (ra & 7)) << 4));
            }
            asm volatile("s_waitcnt lgkmcnt(0)" ::: "memory");
            __builtin_amdgcn_sched_barrier(0);
            __builtin_amdgcn_s_setprio(1);
#pragma unroll
            for (int d = 0; d < 2; ++d)
#pragma unroll
                for (int kk = 0; kk < 2; ++kk)
#pragma unroll
                    for (int n = 0; n < 4; ++n)
                        acc[2 * p + d][n] = __builtin_amdgcn_mfma_f32_16x16x32_bf16(
                            bfr[n][kk], afr[d][kk], acc[2 * p + d][n], 0, 0, 0);
            __builtin_amdgcn_s_setprio(0);
            __builtin_amdgcn_s_barrier();      // phase-lock (raw: no vmcnt drain)
        }
    }

    // ---- epilogue: D row = n-local (g*4+r), col = m-local (lr); scatter Q/K/V ----
    const int region = n0 >> 10;    // 256-tiles never straddle the 1024 boundaries
#pragma unroll
    for (int fm = 0; fm < 8; ++fm) {
        const int m = m0 + wm + fm * 16 + lr;
        const int b = m >> 11, tt = m & 2047;
        // sigma-permuted token slot for V^T: within each 32-token block,
        // t=16u+4gg+rr -> slot gg*8 + u*4 + rr (matches attn's register-direct P)
        const int ts = (tt & ~31) | (((tt >> 2) & 3) << 3) | (((tt >> 4) & 1) << 2) | (tt & 3);
#pragma unroll
        for (int fn = 0; fn < 4; ++fn) {
            const int nb = n0 + wn + fn * 16 + g * 4;   // 4 consecutive n
            const int cc = nb & 1023;
            const int h = cc >> 6, d0 = cc & 63;
            const size_t bh = (size_t)(b * NHEAD + h);
            if (region == 2) {
#pragma unroll
                for (int r2 = 0; r2 < 4; ++r2)
                    Vt[(bh * HDIM + d0 + r2) * TSEQ + ts] = (bf16_t)acc[fm][fn][r2];
            } else {
                bf16x4 w;
#pragma unroll
                for (int r2 = 0; r2 < 4; ++r2) w[r2] = (bf16_t)acc[fm][fn][r2];
                bf16_t* dst = (region == 0) ? Qb : Kb;
                *(bf16x4*)(dst + (bh * TSEQ + tt) * HDIM + d0) = w;
            }
        }
    }
}

// ---------------- GEMM2: C[M][N] = A[M][1024] * Bt[N][1024]^T + bias (f32 out) ----------------
// Counted-vmcnt pipeline (round-14 proven), 128x64 tiles, 512 blocks = 2/CU.
template<int NB, int FN>
__global__ __launch_bounds__(256)
void gemm_bf16(const bf16_t* __restrict__ Ab, const bf16_t* __restrict__ Bt,
               float* __restrict__ Cout, const float* __restrict__ bias)
{
    __shared__ __align__(16) bf16_t As[3][128][32];
    __shared__ __align__(16) bf16_t Bs[3][FN * 32][32];

    constexpr int NXC = NB / 8;
    const int xcd = blockIdx.x & 7;
    const int r   = blockIdx.x >> 3;
    const int m0 = (r / NXC) * 128;
    const int n0 = (xcd * NXC + r % NXC) * (FN * 32);

    const int tid  = threadIdx.x;
    const int lane = tid & 63;
    const int wave = tid >> 6;
    const int wm = (wave >> 1) * 64, wn = (wave & 1) * (FN * 16);
    const int g = lane >> 4, lr = lane & 15;

    f32x4 acc[4][FN];
#pragma unroll
    for (int i = 0; i < 4; ++i)
#pragma unroll
        for (int j = 0; j < FN; ++j) acc[i][j] = f32x4{0.f, 0.f, 0.f, 0.f};

    auto stage = [&](int k0, int buf) {
#pragma unroll
        for (int c = 0; c < 2; ++c) {
            int idx  = tid + c * 256;
            int row  = idx >> 2;
            int csrc = (idx & 3) ^ ((row >> 1) & 3);
            GLL(Ab + (size_t)(m0 + row) * 1024 + k0 + csrc * 8,
                (char*)&As[buf][0][0] + (c * 256 + wave * 64) * 16);
            if (c < FN / 2)
                GLL(Bt + (size_t)(n0 + row) * 1024 + k0 + csrc * 8,
                    (char*)&Bs[buf][0][0] + (c * 256 + wave * 64) * 16);
        }
    };

    stage(0, 0);
    stage(32, 1);

    for (int t = 0; t < 32; ++t) {
        if (t < 31) asm volatile("s_waitcnt vmcnt(3)" ::: "memory");
        else        asm volatile("s_waitcnt vmcnt(0)" ::: "memory");
        __builtin_amdgcn_s_barrier();
        __builtin_amdgcn_sched_barrier(0);
        if (t + 2 < 32) stage((t + 2) * 32, (t + 2) % 3);

        const int buf = t % 3;
        const char* Ac = (const char*)&As[buf][0][0];
        const char* Bc = (const char*)&Bs[buf][0][0];
        bf16x8 afr[4], bfr[FN];
#pragma unroll
        for (int f = 0; f < 4; ++f) {
            int ra = wm + f * 16 + lr;
            afr[f] = *(const bf16x8*)(Ac + ra * 64 + ((g ^ ((ra >> 1) & 3)) << 4));
        }
#pragma unroll
        for (int f = 0; f < FN; ++f) {
            int rb = wn + f * 16 + lr;
            bfr[f] = *(const bf16x8*)(Bc + rb * 64 + ((g ^ ((rb >> 1) & 3)) << 4));
        }
        __builtin_amdgcn_s_setprio(1);
#pragma unroll
        for (int fm = 0; fm < 4; ++fm)
#pragma unroll
            for (int fn = 0; fn < FN; ++fn)
                acc[fm][fn] = __builtin_amdgcn_mfma_f32_16x16x32_bf16(bfr[fn], afr[fm], acc[fm][fn], 0, 0, 0);
        __builtin_amdgcn_s_setprio(0);
    }

#pragma unroll
    for (int fm = 0; fm < 4; ++fm) {
        const int m = m0 + wm + fm * 16 + lr;
#pragma unroll
        for (int fn = 0; fn < FN; ++fn) {
            const int nb = n0 + wn + fn * 16 + g * 4;
            float4 bb = *(const float4*)(bias + nb);
            float4 v;
            v.x = acc[fm][fn][0] + bb.x;
            v.y = acc[fm][fn][1] + bb.y;
            v.z = acc[fm][fn][2] + bb.z;
            v.w = acc[fm][fn][3] + bb.w;
            *(float4*)(Cout + (size_t)m * DIM + nb) = v;
        }
    }
}

// ---------------- flash attention v12b (round-18, unchanged) ----------------
__global__ __launch_bounds__(256, 2)
void attn_kernel(const bf16_t* __restrict__ Qb, const bf16_t* __restrict__ Kb,
                 const bf16_t* __restrict__ Vt, bf16_t* __restrict__ ctx,
                 const float* __restrict__ w_sigma)
{
    __shared__ __align__(16) bf16_t Ktile[4][64][64];   // [s][d] rows 128B, 16B-chunk XOR (row&7)
    __shared__ __align__(16) bf16_t Vtile[4][64][64];   // [d][s'] rows 128B, same XOR; s' sigma-permuted

    const int l    = ((blockIdx.x & 7) << 6) + (blockIdx.x >> 3);   // bijective XCD swizzle, 512 blocks
    const int qc   = l & 15;
    const int bh   = l >> 4;
    const int h    = bh & 15;
    const int b    = bh >> 4;
    const int tid  = threadIdx.x;
    const int lane = tid & 63;
    const int wave = tid >> 6;
    const int g = lane >> 4, lr = lane & 15;
    const int q0 = qc * 128 + wave * 32;

    const float sig = 1.f / (1.f + __expf(-w_sigma[0]));
    const float fl2 = ((h < NTIME) ? (-sig * SCALE_F) : SCALE_F) * LOG2E;

    const bf16_t* Qp = Qb + (size_t)bh * TSEQ * HDIM;
    const bf16_t* Kp = Kb + (size_t)bh * TSEQ * HDIM;
    const bf16_t* Vp = Vt + (size_t)bh * HDIM * TSEQ;

    bf16x8 qa0 = *(const bf16x8*)(Qp + (size_t)(q0 + lr) * HDIM + g * 8);
    bf16x8 qa1 = *(const bf16x8*)(Qp + (size_t)(q0 + lr) * HDIM + 32 + g * 8);
    bf16x8 qb0 = *(const bf16x8*)(Qp + (size_t)(q0 + 16 + lr) * HDIM + g * 8);
    bf16x8 qb1 = *(const bf16x8*)(Qp + (size_t)(q0 + 16 + lr) * HDIM + 32 + g * 8);
#pragma unroll
    for (int e = 0; e < 8; ++e) {
        qa0[e] = (bf16_t)((float)qa0[e] * fl2);
        qa1[e] = (bf16_t)((float)qa1[e] * fl2);
        qb0[e] = (bf16_t)((float)qb0[e] * fl2);
        qb1[e] = (bf16_t)((float)qb1[e] * fl2);
    }

    f32x4 oA[4], oB[4];
#pragma unroll
    for (int n = 0; n < 4; ++n) { oA[n] = f32x4{0.f,0.f,0.f,0.f}; oB[n] = f32x4{0.f,0.f,0.f,0.f}; }
    float lpA = 0.f, lpB = 0.f;

    const int trow = tid >> 3;
    const int tcg  = tid & 7;

    auto stage = [&](int s0, int buf) {
#pragma unroll
        for (int j = 0; j < 2; ++j) {
            int kr = j * 32 + trow;
            GLL(Kp + (size_t)(s0 + kr) * HDIM + ((tcg ^ (kr & 7)) << 3),
                (char*)&Ktile[buf][0][0] + (j * 256 + wave * 64) * 16);
            int vr = j * 32 + trow;
            GLL(Vp + (size_t)vr * TSEQ + s0 + ((tcg ^ (vr & 7)) << 3),
                (char*)&Vtile[buf][0][0] + (j * 256 + wave * 64) * 16);
        }
    };

    auto compute = [&](const char* Kt, const char* Vc) {
        bf16x8 paA[2], paB[2];
        __builtin_amdgcn_s_setprio(1);
#pragma unroll
        for (int st = 0; st < 4; ++st) {
            const int srow = st * 16 + lr;
            const int rs7 = lr & 7;
            bf16x8 kb0 = *(const bf16x8*)(Kt + srow * 128 + ((g ^ rs7) << 4));
            bf16x8 kb1 = *(const bf16x8*)(Kt + srow * 128 + (((4 + g) ^ rs7) << 4));
            f32x4 zA = f32x4{0.f,0.f,0.f,0.f}, zB = f32x4{0.f,0.f,0.f,0.f};
            zA = __builtin_amdgcn_mfma_f32_16x16x32_bf16(kb0, qa0, zA, 0, 0, 0);
            zA = __builtin_amdgcn_mfma_f32_16x16x32_bf16(kb1, qa1, zA, 0, 0, 0);
            zB = __builtin_amdgcn_mfma_f32_16x16x32_bf16(kb0, qb0, zB, 0, 0, 0);
            zB = __builtin_amdgcn_mfma_f32_16x16x32_bf16(kb1, qb1, zB, 0, 0, 0);
            float a0 = __builtin_amdgcn_exp2f(zA[0]);
            float a1 = __builtin_amdgcn_exp2f(zA[1]);
            float a2 = __builtin_amdgcn_exp2f(zA[2]);
            float a3 = __builtin_amdgcn_exp2f(zA[3]);
            float b0 = __builtin_amdgcn_exp2f(zB[0]);
            float b1 = __builtin_amdgcn_exp2f(zB[1]);
            float b2 = __builtin_amdgcn_exp2f(zB[2]);
            float b3 = __builtin_amdgcn_exp2f(zB[3]);
            const int kc = st >> 1, e0 = (st & 1) * 4;
            paA[kc][e0]     = (bf16_t)a0; paA[kc][e0 + 1] = (bf16_t)a1;
            paA[kc][e0 + 2] = (bf16_t)a2; paA[kc][e0 + 3] = (bf16_t)a3;
            paB[kc][e0]     = (bf16_t)b0; paB[kc][e0 + 1] = (bf16_t)b1;
            paB[kc][e0 + 2] = (bf16_t)b2; paB[kc][e0 + 3] = (bf16_t)b3;
            lpA += (a0 + a1) + (a2 + a3);
            lpB += (b0 + b1) + (b2 + b3);
        }
        __builtin_amdgcn_s_setprio(0);

        __builtin_amdgcn_s_setprio(1);
#pragma unroll
        for (int kc = 0; kc < 2; ++kc) {
#pragma unroll
            for (int n = 0; n < 4; ++n) {
                const int row = n * 16 + lr;
                bf16x8 vb = *(const bf16x8*)(Vc + row * 128 + (((kc * 4 + g) ^ (row & 7)) << 4));
                oA[n] = __builtin_amdgcn_mfma_f32_16x16x32_bf16(vb, paA[kc], oA[n], 0, 0, 0);
                oB[n] = __builtin_amdgcn_mfma_f32_16x16x32_bf16(vb, paB[kc], oB[n], 0, 0, 0);
            }
        }
        __builtin_amdgcn_s_setprio(0);
    };

    stage(0, 0);
    stage(64, 1);

    for (int step = 0; step < 32; ++step) {
        if (step + 2 < 32) stage((step + 2) * 64, (step + 2) & 3);
        if (step < 30)       asm volatile("s_waitcnt vmcnt(8)" ::: "memory");
        else if (step == 30) asm volatile("s_waitcnt vmcnt(4)" ::: "memory");
        else                 asm volatile("s_waitcnt vmcnt(0)" ::: "memory");
        __builtin_amdgcn_s_barrier();
        __builtin_amdgcn_sched_barrier(0);
        const int buf = step & 3;
        compute((const char*)&Ktile[buf][0][0], (const char*)&Vtile[buf][0][0]);
    }

    float lfA = lpA, lfB = lpB;
    lfA += __shfl_xor(lfA, 16, 64);
    lfA += __shfl_xor(lfA, 32, 64);
    lfB += __shfl_xor(lfB, 16, 64);
    lfB += __shfl_xor(lfB, 32, 64);
    float liA = 1.f / lfA, liB = 1.f / lfB;

    const int tA = q0 + lr, tB = q0 + 16 + lr;
#pragma unroll
    for (int n = 0; n < 4; ++n) {
        bf16x4 wA, wB;
#pragma unroll
        for (int r = 0; r < 4; ++r) {
            wA[r] = (bf16_t)(oA[n][r] * liA);
            wB[r] = (bf16_t)(oB[n][r] * liB);
        }
        *(bf16x4*)(ctx + ((size_t)(b * TSEQ + tA)) * DIM + h * HDIM + n * 16 + g * 4) = wA;
        *(bf16x4*)(ctx + ((size_t)(b * TSEQ + tB)) * DIM + h * HDIM + n * 16 + g * 4) = wB;
    }
}

// ---------------- launch ----------------
extern "C" void kernel_launch(void* const* d_in, const int* in_sizes, int n_in,
                              void* d_out, int out_size, void* d_ws, size_t ws_size,
                              hipStream_t stream) {
    const float* x    = (const float*)d_in[0];
    const float* Wqt  = (const float*)d_in[1];
    const float* Wkt  = (const float*)d_in[2];
    const float* Wqs  = (const float*)d_in[3];
    const float* Wks  = (const float*)d_in[4];
    const float* Wv   = (const float*)d_in[5];
    const float* Wout = (const float*)d_in[6];
    const float* bout = (const float*)d_in[7];
    const float* wsig = (const float*)d_in[8];
    (void)in_sizes; (void)n_in; (void)out_size; (void)ws_size;

    char* ws = (char*)d_ws;
    bf16_t* WqkvT = (bf16_t*)(ws + OFF_WQKVT);
    bf16_t* WoutT = (bf16_t*)(ws + OFF_WOUTT);
    bf16_t* Qb    = (bf16_t*)(ws + OFF_Q);
    bf16_t* Kb    = (bf16_t*)(ws + OFF_K);
    bf16_t* Vt    = (bf16_t*)(ws + OFF_VT);
    bf16_t* ctx   = (bf16_t*)(ws + OFF_CTX);
    bf16_t* Xb    = ctx;
    float*  out   = (float*)d_out;

    prep_all<<<3072, 256, 0, stream>>>(x, Wqt, Wkt, Wqs, Wks, Wv, Wout, Xb, WqkvT, WoutT);

    // x @ Wqkv -> Q, K, V: 256^2 phased kernel, 192 blocks x 512 threads
    gemm1_8ph<<<192, 512, 0, stream>>>(Xb, WqkvT, Qb, Kb, Vt);

    // attention (round-18 config): 512 blocks
    attn_kernel<<<512, 256, 0, stream>>>(Qb, Kb, Vt, ctx, wsig);

    // ctx @ Wout + bout -> d_out; 512 blocks (128x64 tiles) = 2/CU
    gemm_bf16<16, 2><<<512, 256, 0, stream>>>(ctx, WoutT, out, bout);
}

// Round 20
// 108.588 us; speedup vs baseline: 1.0593x; 1.0593x over previous
//
#include <hip/hip_runtime.h>
#include <hip/hip_bf16.h>

typedef __bf16 bf16_t;
typedef __bf16 bf16x2 __attribute__((ext_vector_type(2)));
typedef __bf16 bf16x4 __attribute__((ext_vector_type(4)));
typedef __bf16 bf16x8 __attribute__((ext_vector_type(8)));
typedef float  f32x4  __attribute__((ext_vector_type(4)));

#define DIM     1024
#define NHEAD   16
#define HDIM    64
#define NTIME   4
#define TSEQ    2048
#define NBATCH  2
#define SCALE_F 0.125f          // 64^-0.5
#define LOG2E   1.4426950408889634f

// async global->LDS, 16B per lane; LDS dest = wave-uniform base, HW adds lane*16
#define GLL(gp, lp) __builtin_amdgcn_global_load_lds( \
    (const __attribute__((address_space(1))) unsigned int*)(const void*)(gp), \
    (__attribute__((address_space(3))) unsigned int*)(void*)(lp), 16, 0, 0)

// ---------------- workspace layout (bytes) ----------------
#define OFF_WQKVT 0UL                                   // [3072][1024] bf16 (B^T; cols: Q,K,V)
#define OFF_WOUTT (OFF_WQKVT + 3072UL*1024UL*2UL)       // [1024][1024] bf16 (B^T of Wout)
#define OFF_Q     (OFF_WOUTT + 1024UL*1024UL*2UL)       // [B][NH][T][HD] bf16
#define OFF_K     (OFF_Q  + 2UL*16UL*2048UL*64UL*2UL)   // [B][NH][T][HD] bf16
#define OFF_VT    (OFF_K  + 2UL*16UL*2048UL*64UL*2UL)   // [B][NH][HD][T] bf16 (V^T, sigma-permuted per 32-token block)
#define OFF_CTX   (OFF_VT + 2UL*16UL*2048UL*64UL*2UL)   // [4096][1024] bf16 (Xb before attn; final ctx)

// ---------------- fused prep: x->bf16, Wqkv^T, Wout^T in ONE launch ----------------
// Transpose store phase: each lane writes a bf16x2 (2 adjacent k-cols, 4B/lane).
// LDS re-read T[2sc][nl]: stride 130 words -> bank step 2 -> 2-way = free (m136).
__global__ void prep_all(const float* __restrict__ x,
                         const float* __restrict__ Wqt, const float* __restrict__ Wkt,
                         const float* __restrict__ Wqs, const float* __restrict__ Wks,
                         const float* __restrict__ Wv,  const float* __restrict__ Wout,
                         bf16_t* __restrict__ Xb, bf16_t* __restrict__ WqkvT,
                         bf16_t* __restrict__ WoutT) {
    __shared__ float T[64][65];
    const int bid = blockIdx.x;
    if (bid < 2048) {
        int i = bid * 256 + threadIdx.x;
        const float4* s = (const float4*)(x + (size_t)i * 8);
        float4 a = s[0], b2 = s[1];
        bf16x8 v;
        v[0] = (bf16_t)a.x;  v[1] = (bf16_t)a.y;  v[2] = (bf16_t)a.z;  v[3] = (bf16_t)a.w;
        v[4] = (bf16_t)b2.x; v[5] = (bf16_t)b2.y; v[6] = (bf16_t)b2.z; v[7] = (bf16_t)b2.w;
        *(bf16x8*)(Xb + (size_t)i * 8) = v;
        return;
    }
    const int tc = threadIdx.x & 63, tr = threadIdx.x >> 6;   // load partition
    const int sc = threadIdx.x & 31, sr = threadIdx.x >> 5;   // store partition (2 cols/lane)
    if (bid < 2816) {
        const int l = bid - 2048;               // 0..767 = 48 x 16
        const int n0 = (l % 48) * 64;
        const int k0 = (l / 48) * 64;
        const int region = n0 >> 10;
        const int cc = n0 & 1023;
        const int h = cc >> 6;
        const float* src; int ncols, col0;
        if (region == 2) { src = Wv; ncols = 1024; col0 = cc; }
        else if (h < NTIME) { src = (region == 0) ? Wqt : Wkt; ncols = NTIME * HDIM; col0 = h * HDIM; }
        else                { src = (region == 0) ? Wqs : Wks; ncols = (NHEAD - NTIME) * HDIM; col0 = (h - NTIME) * HDIM; }
#pragma unroll
        for (int i = 0; i < 16; ++i) {
            int kl = tr * 16 + i;
            T[kl][tc] = src[(size_t)(k0 + kl) * ncols + col0 + tc];
        }
        __syncthreads();
#pragma unroll
        for (int i = 0; i < 8; ++i) {
            int nl = sr * 8 + i;
            bf16x2 w;
            w[0] = (bf16_t)T[sc * 2][nl];
            w[1] = (bf16_t)T[sc * 2 + 1][nl];
            *(bf16x2*)(WqkvT + (size_t)(n0 + nl) * 1024 + k0 + sc * 2) = w;
        }
    } else {
        const int l = bid - 2816;               // 0..255 = 16 x 16
        const int n0 = (l % 16) * 64;
        const int k0 = (l / 16) * 64;
#pragma unroll
        for (int i = 0; i < 16; ++i) {
            int kl = tr * 16 + i;
            T[kl][tc] = Wout[(size_t)(k0 + kl) * 1024 + n0 + tc];
        }
        __syncthreads();
#pragma unroll
        for (int i = 0; i < 8; ++i) {
            int nl = sr * 8 + i;
            bf16x2 w;
            w[0] = (bf16_t)T[sc * 2][nl];
            w[1] = (bf16_t)T[sc * 2 + 1][nl];
            *(bf16x2*)(WoutT + (size_t)(n0 + nl) * 1024 + k0 + sc * 2) = w;
        }
    }
}

// ---------------- GEMM: C[M][N] = A[M][1024] * Bt[N][1024]^T (A bf16) ----------------
// Counted-vmcnt pipeline (round-14 proven). FN = n-frags per wave: block tile is
// 128 x (FN*32). FN=4 -> 128x128 (GEMM1, 768 blocks = 3/CU); FN=2 -> 128x64
// (GEMM2, 512 blocks = 2/CU).
template<int MODE, int NB, int FN>   // NB = grid width in n-tiles (multiple of 8)
__global__ __launch_bounds__(256)
void gemm_bf16(const bf16_t* __restrict__ Ab, const bf16_t* __restrict__ Bt,
               bf16_t* __restrict__ Qb, bf16_t* __restrict__ Kb, bf16_t* __restrict__ Vt,
               float* __restrict__ Cout, const float* __restrict__ bias)
{
    __shared__ __align__(16) bf16_t As[3][128][32];
    __shared__ __align__(16) bf16_t Bs[3][FN * 32][32];

    constexpr int NXC = NB / 8;
    const int xcd = blockIdx.x & 7;
    const int r   = blockIdx.x >> 3;
    const int m0 = (r / NXC) * 128;
    const int n0 = (xcd * NXC + r % NXC) * (FN * 32);

    const int tid  = threadIdx.x;
    const int lane = tid & 63;
    const int wave = tid >> 6;
    const int wm = (wave >> 1) * 64, wn = (wave & 1) * (FN * 16);
    const int g = lane >> 4, lr = lane & 15;

    f32x4 acc[4][FN];
#pragma unroll
    for (int i = 0; i < 4; ++i)
#pragma unroll
        for (int j = 0; j < FN; ++j) acc[i][j] = f32x4{0.f, 0.f, 0.f, 0.f};

    auto stage = [&](int k0, int buf) {
#pragma unroll
        for (int c = 0; c < 2; ++c) {
            int idx  = tid + c * 256;              // row = idx>>2, chunk = idx&3
            int row  = idx >> 2;
            int csrc = (idx & 3) ^ ((row >> 1) & 3);
            GLL(Ab + (size_t)(m0 + row) * 1024 + k0 + csrc * 8,
                (char*)&As[buf][0][0] + (c * 256 + wave * 64) * 16);
            if (c < FN / 2)
                GLL(Bt + (size_t)(n0 + row) * 1024 + k0 + csrc * 8,
                    (char*)&Bs[buf][0][0] + (c * 256 + wave * 64) * 16);
        }
    };

    // ---- prologue: 2-deep prefetch ----
    stage(0, 0);
    stage(32, 1);

    for (int t = 0; t < 32; ++t) {
        // own-wave vmcnt retires stage(t); stage(t+1) stays in flight
        if (t < 31) {
            if constexpr (FN == 4) asm volatile("s_waitcnt vmcnt(4)" ::: "memory");
            else                   asm volatile("s_waitcnt vmcnt(3)" ::: "memory");
        } else {
            asm volatile("s_waitcnt vmcnt(0)" ::: "memory");
        }
        __builtin_amdgcn_s_barrier();          // raw: no vmcnt(0) drain
        __builtin_amdgcn_sched_barrier(0);
        if (t + 2 < 32) stage((t + 2) * 32, (t + 2) % 3);

        const int buf = t % 3;
        const char* Ac = (const char*)&As[buf][0][0];
        const char* Bc = (const char*)&Bs[buf][0][0];
        bf16x8 afr[4], bfr[FN];
#pragma unroll
        for (int f = 0; f < 4; ++f) {
            int ra = wm + f * 16 + lr;
            afr[f] = *(const bf16x8*)(Ac + ra * 64 + ((g ^ ((ra >> 1) & 3)) << 4));
        }
#pragma unroll
        for (int f = 0; f < FN; ++f) {
            int rb = wn + f * 16 + lr;
            bfr[f] = *(const bf16x8*)(Bc + rb * 64 + ((g ^ ((rb >> 1) & 3)) << 4));
        }
        __builtin_amdgcn_s_setprio(1);
#pragma unroll
        for (int fm = 0; fm < 4; ++fm)
#pragma unroll
            for (int fn = 0; fn < FN; ++fn)
                acc[fm][fn] = __builtin_amdgcn_mfma_f32_16x16x32_bf16(bfr[fn], afr[fm], acc[fm][fn], 0, 0, 0);
        __builtin_amdgcn_s_setprio(0);
    }

    const int region = n0 >> 10;
#pragma unroll
    for (int fm = 0; fm < 4; ++fm) {
        const int m = m0 + wm + fm * 16 + lr;
        const int b = m >> 11, t = m & 2047;
        // sigma-permuted token slot for V^T: within each 32-token block,
        // t=16u+4gg+rr -> slot gg*8 + u*4 + rr (matches attn's register-direct P)
        const int ts = (t & ~31) | (((t >> 2) & 3) << 3) | (((t >> 4) & 1) << 2) | (t & 3);
#pragma unroll
        for (int fn = 0; fn < FN; ++fn) {
            const int nb = n0 + wn + fn * 16 + g * 4;   // 4 consecutive n
            if constexpr (MODE == 1) {
                float4 bb = *(const float4*)(bias + nb);
                float4 v;
                v.x = acc[fm][fn][0] + bb.x;
                v.y = acc[fm][fn][1] + bb.y;
                v.z = acc[fm][fn][2] + bb.z;
                v.w = acc[fm][fn][3] + bb.w;
                *(float4*)(Cout + (size_t)m * DIM + nb) = v;
            } else {
                const int cc = nb & 1023;
                const int h = cc >> 6, d0 = cc & 63;
                const size_t bh = (size_t)(b * NHEAD + h);
                if (region == 2) {
#pragma unroll
                    for (int r2 = 0; r2 < 4; ++r2)
                        Vt[(bh * HDIM + d0 + r2) * TSEQ + ts] = (bf16_t)acc[fm][fn][r2];
                } else {
                    bf16x4 w;
#pragma unroll
                    for (int r2 = 0; r2 < 4; ++r2) w[r2] = (bf16_t)acc[fm][fn][r2];
                    bf16_t* dst = (region == 0) ? Qb : Kb;
                    *(bf16x4*)(dst + (bh * TSEQ + t) * HDIM + d0) = w;
                }
            }
        }
    }
}

// ---------------- flash attention v12b (round-18 best) ----------------
// 4 waves x 32 q, 4-buffer K/V (KVBLK=64), counted vmcnt + raw s_barrier; P stays
// in registers, exp2 packed DIRECTLY into PV A-operand regs pa[kc] (mu-mapping;
// V sigma-permuted by GEMM1). No max-stabilization (scores bounded: |s| < ~2).
__global__ __launch_bounds__(256, 2)
void attn_kernel(const bf16_t* __restrict__ Qb, const bf16_t* __restrict__ Kb,
                 const bf16_t* __restrict__ Vt, bf16_t* __restrict__ ctx,
                 const float* __restrict__ w_sigma)
{
    __shared__ __align__(16) bf16_t Ktile[4][64][64];   // [s][d] rows 128B, 16B-chunk XOR (row&7)
    __shared__ __align__(16) bf16_t Vtile[4][64][64];   // [d][s'] rows 128B, same XOR; s' sigma-permuted

    const int l    = ((blockIdx.x & 7) << 6) + (blockIdx.x >> 3);   // bijective XCD swizzle, 512 blocks
    const int qc   = l & 15;
    const int bh   = l >> 4;
    const int h    = bh & 15;
    const int b    = bh >> 4;
    const int tid  = threadIdx.x;
    const int lane = tid & 63;
    const int wave = tid >> 6;
    const int g = lane >> 4, lr = lane & 15;
    const int q0 = qc * 128 + wave * 32;

    const float sig = 1.f / (1.f + __expf(-w_sigma[0]));
    const float fl2 = ((h < NTIME) ? (-sig * SCALE_F) : SCALE_F) * LOG2E;

    const bf16_t* Qp = Qb + (size_t)bh * TSEQ * HDIM;
    const bf16_t* Kp = Kb + (size_t)bh * TSEQ * HDIM;
    const bf16_t* Vp = Vt + (size_t)bh * HDIM * TSEQ;

    bf16x8 qa0 = *(const bf16x8*)(Qp + (size_t)(q0 + lr) * HDIM + g * 8);
    bf16x8 qa1 = *(const bf16x8*)(Qp + (size_t)(q0 + lr) * HDIM + 32 + g * 8);
    bf16x8 qb0 = *(const bf16x8*)(Qp + (size_t)(q0 + 16 + lr) * HDIM + g * 8);
    bf16x8 qb1 = *(const bf16x8*)(Qp + (size_t)(q0 + 16 + lr) * HDIM + 32 + g * 8);
#pragma unroll
    for (int e = 0; e < 8; ++e) {
        qa0[e] = (bf16_t)((float)qa0[e] * fl2);
        qa1[e] = (bf16_t)((float)qa1[e] * fl2);
        qb0[e] = (bf16_t)((float)qb0[e] * fl2);
        qb1[e] = (bf16_t)((float)qb1[e] * fl2);
    }

    f32x4 oA[4], oB[4];                 // O^T per subtile: o[n][r] = O[q][n*16+g*4+r]
#pragma unroll
    for (int n = 0; n < 4; ++n) { oA[n] = f32x4{0.f,0.f,0.f,0.f}; oB[n] = f32x4{0.f,0.f,0.f,0.f}; }
    float lpA = 0.f, lpB = 0.f;

    const int trow = tid >> 3;          // 0..31
    const int tcg  = tid & 7;

    auto stage = [&](int s0, int buf) {
#pragma unroll
        for (int j = 0; j < 2; ++j) {
            int kr = j * 32 + trow;     // 0..63 (s row)
            GLL(Kp + (size_t)(s0 + kr) * HDIM + ((tcg ^ (kr & 7)) << 3),
                (char*)&Ktile[buf][0][0] + (j * 256 + wave * 64) * 16);
            int vr = j * 32 + trow;     // 0..63 (d row)
            GLL(Vp + (size_t)vr * TSEQ + s0 + ((tcg ^ (vr & 7)) << 3),
                (char*)&Vtile[buf][0][0] + (j * 256 + wave * 64) * 16);
        }
    };

    auto compute = [&](const char* Kt, const char* Vc) {
        // ---- S^T = K Q^T; P = exp2, packed DIRECTLY into PV A-operand regs ----
        bf16x8 paA[2], paB[2];          // pa[kc]: elems (st&1)*4+r for st = kc*2, kc*2+1
        __builtin_amdgcn_s_setprio(1);
#pragma unroll
        for (int st = 0; st < 4; ++st) {
            const int srow = st * 16 + lr;
            const int rs7 = lr & 7;
            bf16x8 kb0 = *(const bf16x8*)(Kt + srow * 128 + ((g ^ rs7) << 4));
            bf16x8 kb1 = *(const bf16x8*)(Kt + srow * 128 + (((4 + g) ^ rs7) << 4));
            f32x4 zA = f32x4{0.f,0.f,0.f,0.f}, zB = f32x4{0.f,0.f,0.f,0.f};
            zA = __builtin_amdgcn_mfma_f32_16x16x32_bf16(kb0, qa0, zA, 0, 0, 0);
            zA = __builtin_amdgcn_mfma_f32_16x16x32_bf16(kb1, qa1, zA, 0, 0, 0);
            zB = __builtin_amdgcn_mfma_f32_16x16x32_bf16(kb0, qb0, zB, 0, 0, 0);
            zB = __builtin_amdgcn_mfma_f32_16x16x32_bf16(kb1, qb1, zB, 0, 0, 0);
            float a0 = __builtin_amdgcn_exp2f(zA[0]);
            float a1 = __builtin_amdgcn_exp2f(zA[1]);
            float a2 = __builtin_amdgcn_exp2f(zA[2]);
            float a3 = __builtin_amdgcn_exp2f(zA[3]);
            float b0 = __builtin_amdgcn_exp2f(zB[0]);
            float b1 = __builtin_amdgcn_exp2f(zB[1]);
            float b2 = __builtin_amdgcn_exp2f(zB[2]);
            float b3 = __builtin_amdgcn_exp2f(zB[3]);
            const int kc = st >> 1, e0 = (st & 1) * 4;
            paA[kc][e0]     = (bf16_t)a0; paA[kc][e0 + 1] = (bf16_t)a1;
            paA[kc][e0 + 2] = (bf16_t)a2; paA[kc][e0 + 3] = (bf16_t)a3;
            paB[kc][e0]     = (bf16_t)b0; paB[kc][e0 + 1] = (bf16_t)b1;
            paB[kc][e0 + 2] = (bf16_t)b2; paB[kc][e0 + 3] = (bf16_t)b3;
            lpA += (a0 + a1) + (a2 + a3);
            lpB += (b0 + b1) + (b2 + b3);
        }
        __builtin_amdgcn_s_setprio(0);

        // ---- O^T += V^T P^T : pa = lane-local registers; vb matches via sigma-store ----
        __builtin_amdgcn_s_setprio(1);
#pragma unroll
        for (int kc = 0; kc < 2; ++kc) {
#pragma unroll
            for (int n = 0; n < 4; ++n) {
                const int row = n * 16 + lr;
                bf16x8 vb = *(const bf16x8*)(Vc + row * 128 + (((kc * 4 + g) ^ (row & 7)) << 4));
                oA[n] = __builtin_amdgcn_mfma_f32_16x16x32_bf16(vb, paA[kc], oA[n], 0, 0, 0);
                oB[n] = __builtin_amdgcn_mfma_f32_16x16x32_bf16(vb, paB[kc], oB[n], 0, 0, 0);
            }
        }
        __builtin_amdgcn_s_setprio(0);
    };

    // ---- prologue: stage tiles 0,1 (2-deep) ----
    stage(0, 0);
    stage(64, 1);

    for (int step = 0; step < 32; ++step) {
        if (step + 2 < 32) stage((step + 2) * 64, (step + 2) & 3);
        // counted wait: stages t+1,t+2 (4 GLL instr each) may stay in flight;
        // anything older (incl. stage(t)) must have landed.
        if (step < 30)       asm volatile("s_waitcnt vmcnt(8)" ::: "memory");
        else if (step == 30) asm volatile("s_waitcnt vmcnt(4)" ::: "memory");
        else                 asm volatile("s_waitcnt vmcnt(0)" ::: "memory");
        __builtin_amdgcn_s_barrier();            // raw barrier: NO vmcnt(0) drain
        __builtin_amdgcn_sched_barrier(0);       // pin: no ds_read hoisted above
        const int buf = step & 3;
        compute((const char*)&Ktile[buf][0][0], (const char*)&Vtile[buf][0][0]);
    }

    // ---- final l reduce across the 4 g-groups ----
    float lfA = lpA, lfB = lpB;
    lfA += __shfl_xor(lfA, 16, 64);
    lfA += __shfl_xor(lfA, 32, 64);
    lfB += __shfl_xor(lfB, 16, 64);
    lfB += __shfl_xor(lfB, 32, 64);
    float liA = 1.f / lfA, liB = 1.f / lfB;

    const int tA = q0 + lr, tB = q0 + 16 + lr;
#pragma unroll
    for (int n = 0; n < 4; ++n) {
        bf16x4 wA, wB;
#pragma unroll
        for (int r = 0; r < 4; ++r) {
            wA[r] = (bf16_t)(oA[n][r] * liA);
            wB[r] = (bf16_t)(oB[n][r] * liB);
        }
        *(bf16x4*)(ctx + ((size_t)(b * TSEQ + tA)) * DIM + h * HDIM + n * 16 + g * 4) = wA;
        *(bf16x4*)(ctx + ((size_t)(b * TSEQ + tB)) * DIM + h * HDIM + n * 16 + g * 4) = wB;
    }
}

// ---------------- launch ----------------
extern "C" void kernel_launch(void* const* d_in, const int* in_sizes, int n_in,
                              void* d_out, int out_size, void* d_ws, size_t ws_size,
                              hipStream_t stream) {
    const float* x    = (const float*)d_in[0];
    const float* Wqt  = (const float*)d_in[1];
    const float* Wkt  = (const float*)d_in[2];
    const float* Wqs  = (const float*)d_in[3];
    const float* Wks  = (const float*)d_in[4];
    const float* Wv   = (const float*)d_in[5];
    const float* Wout = (const float*)d_in[6];
    const float* bout = (const float*)d_in[7];
    const float* wsig = (const float*)d_in[8];
    (void)in_sizes; (void)n_in; (void)out_size; (void)ws_size;

    char* ws = (char*)d_ws;
    bf16_t* WqkvT = (bf16_t*)(ws + OFF_WQKVT);
    bf16_t* WoutT = (bf16_t*)(ws + OFF_WOUTT);
    bf16_t* Qb    = (bf16_t*)(ws + OFF_Q);
    bf16_t* Kb    = (bf16_t*)(ws + OFF_K);
    bf16_t* Vt    = (bf16_t*)(ws + OFF_VT);
    bf16_t* ctx   = (bf16_t*)(ws + OFF_CTX);
    bf16_t* Xb    = ctx;
    float*  out   = (float*)d_out;

    prep_all<<<3072, 256, 0, stream>>>(x, Wqt, Wkt, Wqs, Wks, Wv, Wout, Xb, WqkvT, WoutT);

    // x @ Wqkv -> Q, K (row-major), V (transposed + sigma-permuted); 768 blocks = 3/CU
    gemm_bf16<0, 24, 4><<<768, 256, 0, stream>>>(Xb, WqkvT, Qb, Kb, Vt, nullptr, nullptr);

    // attention (round-18 best config): 512 blocks
    attn_kernel<<<512, 256, 0, stream>>>(Qb, Kb, Vt, ctx, wsig);

    // ctx @ Wout + bout -> d_out; 512 blocks (128x64 tiles) = 2/CU
    gemm_bf16<1, 16, 2><<<512, 256, 0, stream>>>(ctx, WoutT, nullptr, nullptr, nullptr, out, bout);
}

// Round 21
// 108.091 us; speedup vs baseline: 1.0642x; 1.0046x over previous
//
#include <hip/hip_runtime.h>
#include <hip/hip_bf16.h>

typedef __bf16 bf16_t;
typedef __bf16 bf16x2 __attribute__((ext_vector_type(2)));
typedef __bf16 bf16x4 __attribute__((ext_vector_type(4)));
typedef __bf16 bf16x8 __attribute__((ext_vector_type(8)));
typedef float  f32x4  __attribute__((ext_vector_type(4)));

#define DIM     1024
#define NHEAD   16
#define HDIM    64
#define NTIME   4
#define TSEQ    2048
#define NBATCH  2
#define SCALE_F 0.125f          // 64^-0.5
#define LOG2E   1.4426950408889634f

// async global->LDS, 16B per lane; LDS dest = wave-uniform base, HW adds lane*16
#define GLL(gp, lp) __builtin_amdgcn_global_load_lds( \
    (const __attribute__((address_space(1))) unsigned int*)(const void*)(gp), \
    (__attribute__((address_space(3))) unsigned int*)(void*)(lp), 16, 0, 0)

// ---------------- workspace layout (bytes) ----------------
#define OFF_WQKVT 0UL                                   // [3072][1024] bf16 (B^T; cols: Q,K,V)
#define OFF_WOUTT (OFF_WQKVT + 3072UL*1024UL*2UL)       // [1024][1024] bf16 (B^T of Wout)
#define OFF_Q     (OFF_WOUTT + 1024UL*1024UL*2UL)       // [B][NH][T][HD] bf16
#define OFF_K     (OFF_Q  + 2UL*16UL*2048UL*64UL*2UL)   // [B][NH][T][HD] bf16
#define OFF_VT    (OFF_K  + 2UL*16UL*2048UL*64UL*2UL)   // [B][NH][HD][T] bf16 (V^T, sigma-permuted per 32-token block)
#define OFF_CTX   (OFF_VT + 2UL*16UL*2048UL*64UL*2UL)   // [4096][1024] bf16 (Xb before attn; final ctx)

// ---------------- fused prep: x->bf16, Wqkv^T, Wout^T in ONE launch ----------------
__global__ void prep_all(const float* __restrict__ x,
                         const float* __restrict__ Wqt, const float* __restrict__ Wkt,
                         const float* __restrict__ Wqs, const float* __restrict__ Wks,
                         const float* __restrict__ Wv,  const float* __restrict__ Wout,
                         bf16_t* __restrict__ Xb, bf16_t* __restrict__ WqkvT,
                         bf16_t* __restrict__ WoutT) {
    __shared__ float T[64][65];
    const int bid = blockIdx.x;
    if (bid < 2048) {
        int i = bid * 256 + threadIdx.x;
        const float4* s = (const float4*)(x + (size_t)i * 8);
        float4 a = s[0], b2 = s[1];
        bf16x8 v;
        v[0] = (bf16_t)a.x;  v[1] = (bf16_t)a.y;  v[2] = (bf16_t)a.z;  v[3] = (bf16_t)a.w;
        v[4] = (bf16_t)b2.x; v[5] = (bf16_t)b2.y; v[6] = (bf16_t)b2.z; v[7] = (bf16_t)b2.w;
        *(bf16x8*)(Xb + (size_t)i * 8) = v;
        return;
    }
    const int tc = threadIdx.x & 63, tr = threadIdx.x >> 6;   // load partition
    const int sc = threadIdx.x & 31, sr = threadIdx.x >> 5;   // store partition (2 cols/lane)
    if (bid < 2816) {
        const int l = bid - 2048;               // 0..767 = 48 x 16
        const int n0 = (l % 48) * 64;
        const int k0 = (l / 48) * 64;
        const int region = n0 >> 10;
        const int cc = n0 & 1023;
        const int h = cc >> 6;
        const float* src; int ncols, col0;
        if (region == 2) { src = Wv; ncols = 1024; col0 = cc; }
        else if (h < NTIME) { src = (region == 0) ? Wqt : Wkt; ncols = NTIME * HDIM; col0 = h * HDIM; }
        else                { src = (region == 0) ? Wqs : Wks; ncols = (NHEAD - NTIME) * HDIM; col0 = (h - NTIME) * HDIM; }
#pragma unroll
        for (int i = 0; i < 16; ++i) {
            int kl = tr * 16 + i;
            T[kl][tc] = src[(size_t)(k0 + kl) * ncols + col0 + tc];
        }
        __syncthreads();
#pragma unroll
        for (int i = 0; i < 8; ++i) {
            int nl = sr * 8 + i;
            bf16x2 w;
            w[0] = (bf16_t)T[sc * 2][nl];
            w[1] = (bf16_t)T[sc * 2 + 1][nl];
            *(bf16x2*)(WqkvT + (size_t)(n0 + nl) * 1024 + k0 + sc * 2) = w;
        }
    } else {
        const int l = bid - 2816;               // 0..255 = 16 x 16
        const int n0 = (l % 16) * 64;
        const int k0 = (l / 16) * 64;
#pragma unroll
        for (int i = 0; i < 16; ++i) {
            int kl = tr * 16 + i;
            T[kl][tc] = Wout[(size_t)(k0 + kl) * 1024 + n0 + tc];
        }
        __syncthreads();
#pragma unroll
        for (int i = 0; i < 8; ++i) {
            int nl = sr * 8 + i;
            bf16x2 w;
            w[0] = (bf16_t)T[sc * 2][nl];
            w[1] = (bf16_t)T[sc * 2 + 1][nl];
            *(bf16x2*)(WoutT + (size_t)(n0 + nl) * 1024 + k0 + sc * 2) = w;
        }
    }
}

// ---------------- GEMM1: depth-differentiated prefetch (A 3-deep, B 2-deep) ----------------
// 128x128 tile, BK=32, 768 blocks, 40KB LDS -> 4 blocks/CU (16 waves/CU).
// A streams (first-read L3/HBM ~900cy) -> depth 2 (cover 2 iters); B is L2-resident
// per XCD (n-major chunking) -> depth 1 suffices. Per iter: vmcnt(2) retires
// {A(t),B(t)} keeping A(t+1) in flight (queue order A(t),B(t),A(t+1) maintained by
// issuing B(t+1) BEFORE A(t+2)); raw s_barrier (no drain); stage; compute.
// WAR: both stages write buffers whose readers ran in iter t-1, certified by the
// top-of-t barrier (reads complete before barrier arrival in program order).
__global__ __launch_bounds__(256, 4)
void gemm1(const bf16_t* __restrict__ Ab, const bf16_t* __restrict__ Bt,
           bf16_t* __restrict__ Qb, bf16_t* __restrict__ Kb, bf16_t* __restrict__ Vt)
{
    __shared__ __align__(16) bf16_t As[3][128][32];   // 24 KB
    __shared__ __align__(16) bf16_t Bs[2][128][32];   // 16 KB

    const int xcd = blockIdx.x & 7;          // n-major XCD chunking, NB=24, NXC=3
    const int r   = blockIdx.x >> 3;
    const int m0 = (r / 3) * 128;
    const int n0 = (xcd * 3 + r % 3) * 128;

    const int tid  = threadIdx.x;
    const int lane = tid & 63;
    const int wave = tid >> 6;
    const int wm = (wave >> 1) * 64, wn = (wave & 1) * 64;
    const int g = lane >> 4, lr = lane & 15;

    f32x4 acc[4][4];
#pragma unroll
    for (int i = 0; i < 4; ++i)
#pragma unroll
        for (int j = 0; j < 4; ++j) acc[i][j] = f32x4{0.f, 0.f, 0.f, 0.f};

    // per-stage: 2 GLL/thread (512 chunks cover 128x32)
    auto stageA = [&](int k0, int buf) {
#pragma unroll
        for (int c = 0; c < 2; ++c) {
            int idx  = tid + c * 256;              // row = idx>>2, chunk = idx&3
            int row  = idx >> 2;
            int csrc = (idx & 3) ^ ((row >> 1) & 3);
            GLL(Ab + (size_t)(m0 + row) * 1024 + k0 + csrc * 8,
                (char*)&As[buf][0][0] + (c * 256 + wave * 64) * 16);
        }
    };
    auto stageB = [&](int k0, int buf) {
#pragma unroll
        for (int c = 0; c < 2; ++c) {
            int idx  = tid + c * 256;
            int row  = idx >> 2;
            int csrc = (idx & 3) ^ ((row >> 1) & 3);
            GLL(Bt + (size_t)(n0 + row) * 1024 + k0 + csrc * 8,
                (char*)&Bs[buf][0][0] + (c * 256 + wave * 64) * 16);
        }
    };

    // ---- prologue establishes queue invariant: A(0), B(0), A(1) ----
    stageA(0, 0);
    stageB(0, 0);
    stageA(32, 1);

    for (int t = 0; t < 32; ++t) {
        // queue (oldest->newest): A(t):2, B(t):2, A(t+1):2  -> vmcnt(2) retires A(t),B(t)
        if (t < 31) asm volatile("s_waitcnt vmcnt(2)" ::: "memory");
        else        asm volatile("s_waitcnt vmcnt(0)" ::: "memory");
        __builtin_amdgcn_s_barrier();          // raw: no vmcnt(0) drain
        __builtin_amdgcn_sched_barrier(0);
        if (t + 1 < 32) stageB((t + 1) * 32, (t + 1) & 1);   // issue B BEFORE A (queue order)
        if (t + 2 < 32) stageA((t + 2) * 32, (t + 2) % 3);

        const char* Ac = (const char*)&As[t % 3][0][0];
        const char* Bc = (const char*)&Bs[t & 1][0][0];
        bf16x8 afr[4], bfr[4];
#pragma unroll
        for (int f = 0; f < 4; ++f) {
            int ra = wm + f * 16 + lr;
            afr[f] = *(const bf16x8*)(Ac + ra * 64 + ((g ^ ((ra >> 1) & 3)) << 4));
            int rb = wn + f * 16 + lr;
            bfr[f] = *(const bf16x8*)(Bc + rb * 64 + ((g ^ ((rb >> 1) & 3)) << 4));
        }
        __builtin_amdgcn_s_setprio(1);
#pragma unroll
        for (int fm = 0; fm < 4; ++fm)
#pragma unroll
            for (int fn = 0; fn < 4; ++fn)
                acc[fm][fn] = __builtin_amdgcn_mfma_f32_16x16x32_bf16(bfr[fn], afr[fm], acc[fm][fn], 0, 0, 0);
        __builtin_amdgcn_s_setprio(0);
    }

    // ---- epilogue: D row = n-local (g*4+r), col = m-local (lr); scatter Q/K/V ----
    const int region = n0 >> 10;
#pragma unroll
    for (int fm = 0; fm < 4; ++fm) {
        const int m = m0 + wm + fm * 16 + lr;
        const int b = m >> 11, t = m & 2047;
        // sigma-permuted token slot for V^T: within each 32-token block,
        // t=16u+4gg+rr -> slot gg*8 + u*4 + rr (matches attn's register-direct P)
        const int ts = (t & ~31) | (((t >> 2) & 3) << 3) | (((t >> 4) & 1) << 2) | (t & 3);
#pragma unroll
        for (int fn = 0; fn < 4; ++fn) {
            const int nb = n0 + wn + fn * 16 + g * 4;   // 4 consecutive n
            const int cc = nb & 1023;
            const int h = cc >> 6, d0 = cc & 63;
            const size_t bh = (size_t)(b * NHEAD + h);
            if (region == 2) {
#pragma unroll
                for (int r2 = 0; r2 < 4; ++r2)
                    Vt[(bh * HDIM + d0 + r2) * TSEQ + ts] = (bf16_t)acc[fm][fn][r2];
            } else {
                bf16x4 w;
#pragma unroll
                for (int r2 = 0; r2 < 4; ++r2) w[r2] = (bf16_t)acc[fm][fn][r2];
                bf16_t* dst = (region == 0) ? Qb : Kb;
                *(bf16x4*)(dst + (bh * TSEQ + t) * HDIM + d0) = w;
            }
        }
    }
}

// ---------------- GEMM2: counted-vmcnt pipeline (round-14 proven), 128x64 tiles ----------------
template<int NB, int FN>
__global__ __launch_bounds__(256)
void gemm_out(const bf16_t* __restrict__ Ab, const bf16_t* __restrict__ Bt,
              float* __restrict__ Cout, const float* __restrict__ bias)
{
    __shared__ __align__(16) bf16_t As[3][128][32];
    __shared__ __align__(16) bf16_t Bs[3][FN * 32][32];

    constexpr int NXC = NB / 8;
    const int xcd = blockIdx.x & 7;
    const int r   = blockIdx.x >> 3;
    const int m0 = (r / NXC) * 128;
    const int n0 = (xcd * NXC + r % NXC) * (FN * 32);

    const int tid  = threadIdx.x;
    const int lane = tid & 63;
    const int wave = tid >> 6;
    const int wm = (wave >> 1) * 64, wn = (wave & 1) * (FN * 16);
    const int g = lane >> 4, lr = lane & 15;

    f32x4 acc[4][FN];
#pragma unroll
    for (int i = 0; i < 4; ++i)
#pragma unroll
        for (int j = 0; j < FN; ++j) acc[i][j] = f32x4{0.f, 0.f, 0.f, 0.f};

    auto stage = [&](int k0, int buf) {
#pragma unroll
        for (int c = 0; c < 2; ++c) {
            int idx  = tid + c * 256;
            int row  = idx >> 2;
            int csrc = (idx & 3) ^ ((row >> 1) & 3);
            GLL(Ab + (size_t)(m0 + row) * 1024 + k0 + csrc * 8,
                (char*)&As[buf][0][0] + (c * 256 + wave * 64) * 16);
            if (c < FN / 2)
                GLL(Bt + (size_t)(n0 + row) * 1024 + k0 + csrc * 8,
                    (char*)&Bs[buf][0][0] + (c * 256 + wave * 64) * 16);
        }
    };

    stage(0, 0);
    stage(32, 1);

    for (int t = 0; t < 32; ++t) {
        if (t < 31) asm volatile("s_waitcnt vmcnt(3)" ::: "memory");
        else        asm volatile("s_waitcnt vmcnt(0)" ::: "memory");
        __builtin_amdgcn_s_barrier();
        __builtin_amdgcn_sched_barrier(0);
        if (t + 2 < 32) stage((t + 2) * 32, (t + 2) % 3);

        const int buf = t % 3;
        const char* Ac = (const char*)&As[buf][0][0];
        const char* Bc = (const char*)&Bs[buf][0][0];
        bf16x8 afr[4], bfr[FN];
#pragma unroll
        for (int f = 0; f < 4; ++f) {
            int ra = wm + f * 16 + lr;
            afr[f] = *(const bf16x8*)(Ac + ra * 64 + ((g ^ ((ra >> 1) & 3)) << 4));
        }
#pragma unroll
        for (int f = 0; f < FN; ++f) {
            int rb = wn + f * 16 + lr;
            bfr[f] = *(const bf16x8*)(Bc + rb * 64 + ((g ^ ((rb >> 1) & 3)) << 4));
        }
        __builtin_amdgcn_s_setprio(1);
#pragma unroll
        for (int fm = 0; fm < 4; ++fm)
#pragma unroll
            for (int fn = 0; fn < FN; ++fn)
                acc[fm][fn] = __builtin_amdgcn_mfma_f32_16x16x32_bf16(bfr[fn], afr[fm], acc[fm][fn], 0, 0, 0);
        __builtin_amdgcn_s_setprio(0);
    }

#pragma unroll
    for (int fm = 0; fm < 4; ++fm) {
        const int m = m0 + wm + fm * 16 + lr;
#pragma unroll
        for (int fn = 0; fn < FN; ++fn) {
            const int nb = n0 + wn + fn * 16 + g * 4;
            float4 bb = *(const float4*)(bias + nb);
            float4 v;
            v.x = acc[fm][fn][0] + bb.x;
            v.y = acc[fm][fn][1] + bb.y;
            v.z = acc[fm][fn][2] + bb.z;
            v.w = acc[fm][fn][3] + bb.w;
            *(float4*)(Cout + (size_t)m * DIM + nb) = v;
        }
    }
}

// ---------------- flash attention v12b (round-18 best, unchanged) ----------------
__global__ __launch_bounds__(256, 2)
void attn_kernel(const bf16_t* __restrict__ Qb, const bf16_t* __restrict__ Kb,
                 const bf16_t* __restrict__ Vt, bf16_t* __restrict__ ctx,
                 const float* __restrict__ w_sigma)
{
    __shared__ __align__(16) bf16_t Ktile[4][64][64];   // [s][d] rows 128B, 16B-chunk XOR (row&7)
    __shared__ __align__(16) bf16_t Vtile[4][64][64];   // [d][s'] rows 128B, same XOR; s' sigma-permuted

    const int l    = ((blockIdx.x & 7) << 6) + (blockIdx.x >> 3);   // bijective XCD swizzle, 512 blocks
    const int qc   = l & 15;
    const int bh   = l >> 4;
    const int h    = bh & 15;
    const int b    = bh >> 4;
    const int tid  = threadIdx.x;
    const int lane = tid & 63;
    const int wave = tid >> 6;
    const int g = lane >> 4, lr = lane & 15;
    const int q0 = qc * 128 + wave * 32;

    const float sig = 1.f / (1.f + __expf(-w_sigma[0]));
    const float fl2 = ((h < NTIME) ? (-sig * SCALE_F) : SCALE_F) * LOG2E;

    const bf16_t* Qp = Qb + (size_t)bh * TSEQ * HDIM;
    const bf16_t* Kp = Kb + (size_t)bh * TSEQ * HDIM;
    const bf16_t* Vp = Vt + (size_t)bh * HDIM * TSEQ;

    bf16x8 qa0 = *(const bf16x8*)(Qp + (size_t)(q0 + lr) * HDIM + g * 8);
    bf16x8 qa1 = *(const bf16x8*)(Qp + (size_t)(q0 + lr) * HDIM + 32 + g * 8);
    bf16x8 qb0 = *(const bf16x8*)(Qp + (size_t)(q0 + 16 + lr) * HDIM + g * 8);
    bf16x8 qb1 = *(const bf16x8*)(Qp + (size_t)(q0 + 16 + lr) * HDIM + 32 + g * 8);
#pragma unroll
    for (int e = 0; e < 8; ++e) {
        qa0[e] = (bf16_t)((float)qa0[e] * fl2);
        qa1[e] = (bf16_t)((float)qa1[e] * fl2);
        qb0[e] = (bf16_t)((float)qb0[e] * fl2);
        qb1[e] = (bf16_t)((float)qb1[e] * fl2);
    }

    f32x4 oA[4], oB[4];
#pragma unroll
    for (int n = 0; n < 4; ++n) { oA[n] = f32x4{0.f,0.f,0.f,0.f}; oB[n] = f32x4{0.f,0.f,0.f,0.f}; }
    float lpA = 0.f, lpB = 0.f;

    const int trow = tid >> 3;
    const int tcg  = tid & 7;

    auto stage = [&](int s0, int buf) {
#pragma unroll
        for (int j = 0; j < 2; ++j) {
            int kr = j * 32 + trow;
            GLL(Kp + (size_t)(s0 + kr) * HDIM + ((tcg ^ (kr & 7)) << 3),
                (char*)&Ktile[buf][0][0] + (j * 256 + wave * 64) * 16);
            int vr = j * 32 + trow;
            GLL(Vp + (size_t)vr * TSEQ + s0 + ((tcg ^ (vr & 7)) << 3),
                (char*)&Vtile[buf][0][0] + (j * 256 + wave * 64) * 16);
        }
    };

    auto compute = [&](const char* Kt, const char* Vc) {
        bf16x8 paA[2], paB[2];
        __builtin_amdgcn_s_setprio(1);
#pragma unroll
        for (int st = 0; st < 4; ++st) {
            const int srow = st * 16 + lr;
            const int rs7 = lr & 7;
            bf16x8 kb0 = *(const bf16x8*)(Kt + srow * 128 + ((g ^ rs7) << 4));
            bf16x8 kb1 = *(const bf16x8*)(Kt + srow * 128 + (((4 + g) ^ rs7) << 4));
            f32x4 zA = f32x4{0.f,0.f,0.f,0.f}, zB = f32x4{0.f,0.f,0.f,0.f};
            zA = __builtin_amdgcn_mfma_f32_16x16x32_bf16(kb0, qa0, zA, 0, 0, 0);
            zA = __builtin_amdgcn_mfma_f32_16x16x32_bf16(kb1, qa1, zA, 0, 0, 0);
            zB = __builtin_amdgcn_mfma_f32_16x16x32_bf16(kb0, qb0, zB, 0, 0, 0);
            zB = __builtin_amdgcn_mfma_f32_16x16x32_bf16(kb1, qb1, zB, 0, 0, 0);
            float a0 = __builtin_amdgcn_exp2f(zA[0]);
            float a1 = __builtin_amdgcn_exp2f(zA[1]);
            float a2 = __builtin_amdgcn_exp2f(zA[2]);
            float a3 = __builtin_amdgcn_exp2f(zA[3]);
            float b0 = __builtin_amdgcn_exp2f(zB[0]);
            float b1 = __builtin_amdgcn_exp2f(zB[1]);
            float b2 = __builtin_amdgcn_exp2f(zB[2]);
            float b3 = __builtin_amdgcn_exp2f(zB[3]);
            const int kc = st >> 1, e0 = (st & 1) * 4;
            paA[kc][e0]     = (bf16_t)a0; paA[kc][e0 + 1] = (bf16_t)a1;
            paA[kc][e0 + 2] = (bf16_t)a2; paA[kc][e0 + 3] = (bf16_t)a3;
            paB[kc][e0]     = (bf16_t)b0; paB[kc][e0 + 1] = (bf16_t)b1;
            paB[kc][e0 + 2] = (bf16_t)b2; paB[kc][e0 + 3] = (bf16_t)b3;
            lpA += (a0 + a1) + (a2 + a3);
            lpB += (b0 + b1) + (b2 + b3);
        }
        __builtin_amdgcn_s_setprio(0);

        __builtin_amdgcn_s_setprio(1);
#pragma unroll
        for (int kc = 0; kc < 2; ++kc) {
#pragma unroll
            for (int n = 0; n < 4; ++n) {
                const int row = n * 16 + lr;
                bf16x8 vb = *(const bf16x8*)(Vc + row * 128 + (((kc * 4 + g) ^ (row & 7)) << 4));
                oA[n] = __builtin_amdgcn_mfma_f32_16x16x32_bf16(vb, paA[kc], oA[n], 0, 0, 0);
                oB[n] = __builtin_amdgcn_mfma_f32_16x16x32_bf16(vb, paB[kc], oB[n], 0, 0, 0);
            }
        }
        __builtin_amdgcn_s_setprio(0);
    };

    stage(0, 0);
    stage(64, 1);

    for (int step = 0; step < 32; ++step) {
        if (step + 2 < 32) stage((step + 2) * 64, (step + 2) & 3);
        if (step < 30)       asm volatile("s_waitcnt vmcnt(8)" ::: "memory");
        else if (step == 30) asm volatile("s_waitcnt vmcnt(4)" ::: "memory");
        else                 asm volatile("s_waitcnt vmcnt(0)" ::: "memory");
        __builtin_amdgcn_s_barrier();
        __builtin_amdgcn_sched_barrier(0);
        const int buf = step & 3;
        compute((const char*)&Ktile[buf][0][0], (const char*)&Vtile[buf][0][0]);
    }

    float lfA = lpA, lfB = lpB;
    lfA += __shfl_xor(lfA, 16, 64);
    lfA += __shfl_xor(lfA, 32, 64);
    lfB += __shfl_xor(lfB, 16, 64);
    lfB += __shfl_xor(lfB, 32, 64);
    float liA = 1.f / lfA, liB = 1.f / lfB;

    const int tA = q0 + lr, tB = q0 + 16 + lr;
#pragma unroll
    for (int n = 0; n < 4; ++n) {
        bf16x4 wA, wB;
#pragma unroll
        for (int r = 0; r < 4; ++r) {
            wA[r] = (bf16_t)(oA[n][r] * liA);
            wB[r] = (bf16_t)(oB[n][r] * liB);
        }
        *(bf16x4*)(ctx + ((size_t)(b * TSEQ + tA)) * DIM + h * HDIM + n * 16 + g * 4) = wA;
        *(bf16x4*)(ctx + ((size_t)(b * TSEQ + tB)) * DIM + h * HDIM + n * 16 + g * 4) = wB;
    }
}

// ---------------- launch ----------------
extern "C" void kernel_launch(void* const* d_in, const int* in_sizes, int n_in,
                              void* d_out, int out_size, void* d_ws, size_t ws_size,
                              hipStream_t stream) {
    const float* x    = (const float*)d_in[0];
    const float* Wqt  = (const float*)d_in[1];
    const float* Wkt  = (const float*)d_in[2];
    const float* Wqs  = (const float*)d_in[3];
    const float* Wks  = (const float*)d_in[4];
    const float* Wv   = (const float*)d_in[5];
    const float* Wout = (const float*)d_in[6];
    const float* bout = (const float*)d_in[7];
    const float* wsig = (const float*)d_in[8];
    (void)in_sizes; (void)n_in; (void)out_size; (void)ws_size;

    char* ws = (char*)d_ws;
    bf16_t* WqkvT = (bf16_t*)(ws + OFF_WQKVT);
    bf16_t* WoutT = (bf16_t*)(ws + OFF_WOUTT);
    bf16_t* Qb    = (bf16_t*)(ws + OFF_Q);
    bf16_t* Kb    = (bf16_t*)(ws + OFF_K);
    bf16_t* Vt    = (bf16_t*)(ws + OFF_VT);
    bf16_t* ctx   = (bf16_t*)(ws + OFF_CTX);
    bf16_t* Xb    = ctx;
    float*  out   = (float*)d_out;

    prep_all<<<3072, 256, 0, stream>>>(x, Wqt, Wkt, Wqs, Wks, Wv, Wout, Xb, WqkvT, WoutT);

    // x @ Wqkv -> Q, K, V; depth-differentiated prefetch, 768 blocks = 4/CU-capable
    gemm1<<<768, 256, 0, stream>>>(Xb, WqkvT, Qb, Kb, Vt);

    // attention (round-18 best config): 512 blocks
    attn_kernel<<<512, 256, 0, stream>>>(Qb, Kb, Vt, ctx, wsig);

    // ctx @ Wout + bout -> d_out; 512 blocks (128x64 tiles) = 2/CU
    gemm_out<16, 2><<<512, 256, 0, stream>>>(ctx, WoutT, out, bout);
}

// Round 22
// 107.121 us; speedup vs baseline: 1.0738x; 1.0091x over previous
//
#include <hip/hip_runtime.h>
#include <hip/hip_bf16.h>

typedef __bf16 bf16_t;
typedef __bf16 bf16x2 __attribute__((ext_vector_type(2)));
typedef __bf16 bf16x4 __attribute__((ext_vector_type(4)));
typedef __bf16 bf16x8 __attribute__((ext_vector_type(8)));
typedef float  f32x4  __attribute__((ext_vector_type(4)));

#define DIM     1024
#define NHEAD   16
#define HDIM    64
#define NTIME   4
#define TSEQ    2048
#define NBATCH  2
#define SCALE_F 0.125f          // 64^-0.5
#define LOG2E   1.4426950408889634f

// async global->LDS, 16B per lane; LDS dest = wave-uniform base, HW adds lane*16
#define GLL(gp, lp) __builtin_amdgcn_global_load_lds( \
    (const __attribute__((address_space(1))) unsigned int*)(const void*)(gp), \
    (__attribute__((address_space(3))) unsigned int*)(void*)(lp), 16, 0, 0)

// ---------------- workspace layout (bytes) ----------------
#define OFF_WQKVT 0UL                                   // [3072][1024] bf16 (B^T; cols: Q,K,V)
#define OFF_WOUTT (OFF_WQKVT + 3072UL*1024UL*2UL)       // [1024][1024] bf16 (B^T of Wout)
#define OFF_Q     (OFF_WOUTT + 1024UL*1024UL*2UL)       // [B][NH][T][HD] bf16
#define OFF_K     (OFF_Q  + 2UL*16UL*2048UL*64UL*2UL)   // [B][NH][T][HD] bf16
#define OFF_VT    (OFF_K  + 2UL*16UL*2048UL*64UL*2UL)   // [B][NH][HD][T] bf16 (V^T, sigma-permuted per 32-token block)
#define OFF_CTX   (OFF_VT + 2UL*16UL*2048UL*64UL*2UL)   // [4096][1024] bf16 (Xb before attn; final ctx)

// ---------------- fused prep: x->bf16, Wqkv^T, Wout^T in ONE launch ----------------
__global__ void prep_all(const float* __restrict__ x,
                         const float* __restrict__ Wqt, const float* __restrict__ Wkt,
                         const float* __restrict__ Wqs, const float* __restrict__ Wks,
                         const float* __restrict__ Wv,  const float* __restrict__ Wout,
                         bf16_t* __restrict__ Xb, bf16_t* __restrict__ WqkvT,
                         bf16_t* __restrict__ WoutT) {
    __shared__ float T[64][65];
    const int bid = blockIdx.x;
    if (bid < 2048) {
        int i = bid * 256 + threadIdx.x;
        const float4* s = (const float4*)(x + (size_t)i * 8);
        float4 a = s[0], b2 = s[1];
        bf16x8 v;
        v[0] = (bf16_t)a.x;  v[1] = (bf16_t)a.y;  v[2] = (bf16_t)a.z;  v[3] = (bf16_t)a.w;
        v[4] = (bf16_t)b2.x; v[5] = (bf16_t)b2.y; v[6] = (bf16_t)b2.z; v[7] = (bf16_t)b2.w;
        *(bf16x8*)(Xb + (size_t)i * 8) = v;
        return;
    }
    const int tc = threadIdx.x & 63, tr = threadIdx.x >> 6;   // load partition
    const int sc = threadIdx.x & 31, sr = threadIdx.x >> 5;   // store partition (2 cols/lane)
    if (bid < 2816) {
        const int l = bid - 2048;               // 0..767 = 48 x 16
        const int n0 = (l % 48) * 64;
        const int k0 = (l / 48) * 64;
        const int region = n0 >> 10;
        const int cc = n0 & 1023;
        const int h = cc >> 6;
        const float* src; int ncols, col0;
        if (region == 2) { src = Wv; ncols = 1024; col0 = cc; }
        else if (h < NTIME) { src = (region == 0) ? Wqt : Wkt; ncols = NTIME * HDIM; col0 = h * HDIM; }
        else                { src = (region == 0) ? Wqs : Wks; ncols = (NHEAD - NTIME) * HDIM; col0 = (h - NTIME) * HDIM; }
#pragma unroll
        for (int i = 0; i < 16; ++i) {
            int kl = tr * 16 + i;
            T[kl][tc] = src[(size_t)(k0 + kl) * ncols + col0 + tc];
        }
        __syncthreads();
#pragma unroll
        for (int i = 0; i < 8; ++i) {
            int nl = sr * 8 + i;
            bf16x2 w;
            w[0] = (bf16_t)T[sc * 2][nl];
            w[1] = (bf16_t)T[sc * 2 + 1][nl];
            *(bf16x2*)(WqkvT + (size_t)(n0 + nl) * 1024 + k0 + sc * 2) = w;
        }
    } else {
        const int l = bid - 2816;               // 0..255 = 16 x 16
        const int n0 = (l % 16) * 64;
        const int k0 = (l / 16) * 64;
#pragma unroll
        for (int i = 0; i < 16; ++i) {
            int kl = tr * 16 + i;
            T[kl][tc] = Wout[(size_t)(k0 + kl) * 1024 + n0 + tc];
        }
        __syncthreads();
#pragma unroll
        for (int i = 0; i < 8; ++i) {
            int nl = sr * 8 + i;
            bf16x2 w;
            w[0] = (bf16_t)T[sc * 2][nl];
            w[1] = (bf16_t)T[sc * 2 + 1][nl];
            *(bf16x2*)(WoutT + (size_t)(n0 + nl) * 1024 + k0 + sc * 2) = w;
        }
    }
}

// ---------------- GEMM1: A 3-deep / B 2-deep prefetch + 2D XCD tile grouping ----------------
// 128x128 tile, BK=32, 768 blocks, 40KB LDS -> 4 blocks/CU (16 waves/CU).
// 2D XCD grouping: XCDs form a 4x2 grid over (m,n); XCD (a,b) owns m-panels
// [8a,8a+8) x n-panels [12b,12b+12) -> per-XCD working set 8*256KB + 12*256KB
// = 5MB (~L2-fit) instead of n-major's 8MB A-thrash. Tests the L3-BW theory.
// Pipeline unchanged from round 21 (proven-neutral-or-better): per iter vmcnt(2)
// retires {A(t),B(t)} keeping A(t+1); raw s_barrier; issue B(t+1) then A(t+2).
__global__ __launch_bounds__(256, 4)
void gemm1(const bf16_t* __restrict__ Ab, const bf16_t* __restrict__ Bt,
           bf16_t* __restrict__ Qb, bf16_t* __restrict__ Kb, bf16_t* __restrict__ Vt)
{
    __shared__ __align__(16) bf16_t As[3][128][32];   // 24 KB
    __shared__ __align__(16) bf16_t Bs[2][128][32];   // 16 KB

    // 2D XCD grouping (bijective): xcd = bid&7 (HW round-robins XCDs, m09)
    const int xcd = blockIdx.x & 7;
    const int j   = blockIdx.x >> 3;                     // 0..95
    const int m0 = (((xcd >> 1) * 8)  + j / 12) * 128;   // 4 m-quadrants x 8 panels
    const int n0 = (((xcd & 1) * 12)  + j % 12) * 128;   // 2 n-quadrants x 12 panels

    const int tid  = threadIdx.x;
    const int lane = tid & 63;
    const int wave = tid >> 6;
    const int wm = (wave >> 1) * 64, wn = (wave & 1) * 64;
    const int g = lane >> 4, lr = lane & 15;

    f32x4 acc[4][4];
#pragma unroll
    for (int i = 0; i < 4; ++i)
#pragma unroll
        for (int j2 = 0; j2 < 4; ++j2) acc[i][j2] = f32x4{0.f, 0.f, 0.f, 0.f};

    // per-stage: 2 GLL/thread (512 chunks cover 128x32)
    auto stageA = [&](int k0, int buf) {
#pragma unroll
        for (int c = 0; c < 2; ++c) {
            int idx  = tid + c * 256;              // row = idx>>2, chunk = idx&3
            int row  = idx >> 2;
            int csrc = (idx & 3) ^ ((row >> 1) & 3);
            GLL(Ab + (size_t)(m0 + row) * 1024 + k0 + csrc * 8,
                (char*)&As[buf][0][0] + (c * 256 + wave * 64) * 16);
        }
    };
    auto stageB = [&](int k0, int buf) {
#pragma unroll
        for (int c = 0; c < 2; ++c) {
            int idx  = tid + c * 256;
            int row  = idx >> 2;
            int csrc = (idx & 3) ^ ((row >> 1) & 3);
            GLL(Bt + (size_t)(n0 + row) * 1024 + k0 + csrc * 8,
                (char*)&Bs[buf][0][0] + (c * 256 + wave * 64) * 16);
        }
    };

    // ---- prologue establishes queue invariant: A(0), B(0), A(1) ----
    stageA(0, 0);
    stageB(0, 0);
    stageA(32, 1);

    for (int t = 0; t < 32; ++t) {
        // queue (oldest->newest): A(t):2, B(t):2, A(t+1):2  -> vmcnt(2) retires A(t),B(t)
        if (t < 31) asm volatile("s_waitcnt vmcnt(2)" ::: "memory");
        else        asm volatile("s_waitcnt vmcnt(0)" ::: "memory");
        __builtin_amdgcn_s_barrier();          // raw: no vmcnt(0) drain
        __builtin_amdgcn_sched_barrier(0);
        if (t + 1 < 32) stageB((t + 1) * 32, (t + 1) & 1);   // issue B BEFORE A (queue order)
        if (t + 2 < 32) stageA((t + 2) * 32, (t + 2) % 3);

        const char* Ac = (const char*)&As[t % 3][0][0];
        const char* Bc = (const char*)&Bs[t & 1][0][0];
        bf16x8 afr[4], bfr[4];
#pragma unroll
        for (int f = 0; f < 4; ++f) {
            int ra = wm + f * 16 + lr;
            afr[f] = *(const bf16x8*)(Ac + ra * 64 + ((g ^ ((ra >> 1) & 3)) << 4));
            int rb = wn + f * 16 + lr;
            bfr[f] = *(const bf16x8*)(Bc + rb * 64 + ((g ^ ((rb >> 1) & 3)) << 4));
        }
        __builtin_amdgcn_s_setprio(1);
#pragma unroll
        for (int fm = 0; fm < 4; ++fm)
#pragma unroll
            for (int fn = 0; fn < 4; ++fn)
                acc[fm][fn] = __builtin_amdgcn_mfma_f32_16x16x32_bf16(bfr[fn], afr[fm], acc[fm][fn], 0, 0, 0);
        __builtin_amdgcn_s_setprio(0);
    }

    // ---- epilogue: D row = n-local (g*4+r), col = m-local (lr); scatter Q/K/V ----
    const int region = n0 >> 10;
#pragma unroll
    for (int fm = 0; fm < 4; ++fm) {
        const int m = m0 + wm + fm * 16 + lr;
        const int b = m >> 11, t = m & 2047;
        // sigma-permuted token slot for V^T: within each 32-token block,
        // t=16u+4gg+rr -> slot gg*8 + u*4 + rr (matches attn's register-direct P)
        const int ts = (t & ~31) | (((t >> 2) & 3) << 3) | (((t >> 4) & 1) << 2) | (t & 3);
#pragma unroll
        for (int fn = 0; fn < 4; ++fn) {
            const int nb = n0 + wn + fn * 16 + g * 4;   // 4 consecutive n
            const int cc = nb & 1023;
            const int h = cc >> 6, d0 = cc & 63;
            const size_t bh = (size_t)(b * NHEAD + h);
            if (region == 2) {
#pragma unroll
                for (int r2 = 0; r2 < 4; ++r2)
                    Vt[(bh * HDIM + d0 + r2) * TSEQ + ts] = (bf16_t)acc[fm][fn][r2];
            } else {
                bf16x4 w;
#pragma unroll
                for (int r2 = 0; r2 < 4; ++r2) w[r2] = (bf16_t)acc[fm][fn][r2];
                bf16_t* dst = (region == 0) ? Qb : Kb;
                *(bf16x4*)(dst + (bh * TSEQ + t) * HDIM + d0) = w;
            }
        }
    }
}

// ---------------- GEMM2: counted-vmcnt pipeline (round-14 proven), 128x64 tiles ----------------
template<int NB, int FN>
__global__ __launch_bounds__(256)
void gemm_out(const bf16_t* __restrict__ Ab, const bf16_t* __restrict__ Bt,
              float* __restrict__ Cout, const float* __restrict__ bias)
{
    __shared__ __align__(16) bf16_t As[3][128][32];
    __shared__ __align__(16) bf16_t Bs[3][FN * 32][32];

    constexpr int NXC = NB / 8;
    const int xcd = blockIdx.x & 7;
    const int r   = blockIdx.x >> 3;
    const int m0 = (r / NXC) * 128;
    const int n0 = (xcd * NXC + r % NXC) * (FN * 32);

    const int tid  = threadIdx.x;
    const int lane = tid & 63;
    const int wave = tid >> 6;
    const int wm = (wave >> 1) * 64, wn = (wave & 1) * (FN * 16);
    const int g = lane >> 4, lr = lane & 15;

    f32x4 acc[4][FN];
#pragma unroll
    for (int i = 0; i < 4; ++i)
#pragma unroll
        for (int j = 0; j < FN; ++j) acc[i][j] = f32x4{0.f, 0.f, 0.f, 0.f};

    auto stage = [&](int k0, int buf) {
#pragma unroll
        for (int c = 0; c < 2; ++c) {
            int idx  = tid + c * 256;
            int row  = idx >> 2;
            int csrc = (idx & 3) ^ ((row >> 1) & 3);
            GLL(Ab + (size_t)(m0 + row) * 1024 + k0 + csrc * 8,
                (char*)&As[buf][0][0] + (c * 256 + wave * 64) * 16);
            if (c < FN / 2)
                GLL(Bt + (size_t)(n0 + row) * 1024 + k0 + csrc * 8,
                    (char*)&Bs[buf][0][0] + (c * 256 + wave * 64) * 16);
        }
    };

    stage(0, 0);
    stage(32, 1);

    for (int t = 0; t < 32; ++t) {
        if (t < 31) asm volatile("s_waitcnt vmcnt(3)" ::: "memory");
        else        asm volatile("s_waitcnt vmcnt(0)" ::: "memory");
        __builtin_amdgcn_s_barrier();
        __builtin_amdgcn_sched_barrier(0);
        if (t + 2 < 32) stage((t + 2) * 32, (t + 2) % 3);

        const int buf = t % 3;
        const char* Ac = (const char*)&As[buf][0][0];
        const char* Bc = (const char*)&Bs[buf][0][0];
        bf16x8 afr[4], bfr[FN];
#pragma unroll
        for (int f = 0; f < 4; ++f) {
            int ra = wm + f * 16 + lr;
            afr[f] = *(const bf16x8*)(Ac + ra * 64 + ((g ^ ((ra >> 1) & 3)) << 4));
        }
#pragma unroll
        for (int f = 0; f < FN; ++f) {
            int rb = wn + f * 16 + lr;
            bfr[f] = *(const bf16x8*)(Bc + rb * 64 + ((g ^ ((rb >> 1) & 3)) << 4));
        }
        __builtin_amdgcn_s_setprio(1);
#pragma unroll
        for (int fm = 0; fm < 4; ++fm)
#pragma unroll
            for (int fn = 0; fn < FN; ++fn)
                acc[fm][fn] = __builtin_amdgcn_mfma_f32_16x16x32_bf16(bfr[fn], afr[fm], acc[fm][fn], 0, 0, 0);
        __builtin_amdgcn_s_setprio(0);
    }

#pragma unroll
    for (int fm = 0; fm < 4; ++fm) {
        const int m = m0 + wm + fm * 16 + lr;
#pragma unroll
        for (int fn = 0; fn < FN; ++fn) {
            const int nb = n0 + wn + fn * 16 + g * 4;
            float4 bb = *(const float4*)(bias + nb);
            float4 v;
            v.x = acc[fm][fn][0] + bb.x;
            v.y = acc[fm][fn][1] + bb.y;
            v.z = acc[fm][fn][2] + bb.z;
            v.w = acc[fm][fn][3] + bb.w;
            *(float4*)(Cout + (size_t)m * DIM + nb) = v;
        }
    }
}

// ---------------- flash attention v12b (round-18 best, unchanged) ----------------
__global__ __launch_bounds__(256, 2)
void attn_kernel(const bf16_t* __restrict__ Qb, const bf16_t* __restrict__ Kb,
                 const bf16_t* __restrict__ Vt, bf16_t* __restrict__ ctx,
                 const float* __restrict__ w_sigma)
{
    __shared__ __align__(16) bf16_t Ktile[4][64][64];   // [s][d] rows 128B, 16B-chunk XOR (row&7)
    __shared__ __align__(16) bf16_t Vtile[4][64][64];   // [d][s'] rows 128B, same XOR; s' sigma-permuted

    const int l    = ((blockIdx.x & 7) << 6) + (blockIdx.x >> 3);   // bijective XCD swizzle, 512 blocks
    const int qc   = l & 15;
    const int bh   = l >> 4;
    const int h    = bh & 15;
    const int b    = bh >> 4;
    const int tid  = threadIdx.x;
    const int lane = tid & 63;
    const int wave = tid >> 6;
    const int g = lane >> 4, lr = lane & 15;
    const int q0 = qc * 128 + wave * 32;

    const float sig = 1.f / (1.f + __expf(-w_sigma[0]));
    const float fl2 = ((h < NTIME) ? (-sig * SCALE_F) : SCALE_F) * LOG2E;

    const bf16_t* Qp = Qb + (size_t)bh * TSEQ * HDIM;
    const bf16_t* Kp = Kb + (size_t)bh * TSEQ * HDIM;
    const bf16_t* Vp = Vt + (size_t)bh * HDIM * TSEQ;

    bf16x8 qa0 = *(const bf16x8*)(Qp + (size_t)(q0 + lr) * HDIM + g * 8);
    bf16x8 qa1 = *(const bf16x8*)(Qp + (size_t)(q0 + lr) * HDIM + 32 + g * 8);
    bf16x8 qb0 = *(const bf16x8*)(Qp + (size_t)(q0 + 16 + lr) * HDIM + g * 8);
    bf16x8 qb1 = *(const bf16x8*)(Qp + (size_t)(q0 + 16 + lr) * HDIM + 32 + g * 8);
#pragma unroll
    for (int e = 0; e < 8; ++e) {
        qa0[e] = (bf16_t)((float)qa0[e] * fl2);
        qa1[e] = (bf16_t)((float)qa1[e] * fl2);
        qb0[e] = (bf16_t)((float)qb0[e] * fl2);
        qb1[e] = (bf16_t)((float)qb1[e] * fl2);
    }

    f32x4 oA[4], oB[4];
#pragma unroll
    for (int n = 0; n < 4; ++n) { oA[n] = f32x4{0.f,0.f,0.f,0.f}; oB[n] = f32x4{0.f,0.f,0.f,0.f}; }
    float lpA = 0.f, lpB = 0.f;

    const int trow = tid >> 3;
    const int tcg  = tid & 7;

    auto stage = [&](int s0, int buf) {
#pragma unroll
        for (int j = 0; j < 2; ++j) {
            int kr = j * 32 + trow;
            GLL(Kp + (size_t)(s0 + kr) * HDIM + ((tcg ^ (kr & 7)) << 3),
                (char*)&Ktile[buf][0][0] + (j * 256 + wave * 64) * 16);
            int vr = j * 32 + trow;
            GLL(Vp + (size_t)vr * TSEQ + s0 + ((tcg ^ (vr & 7)) << 3),
                (char*)&Vtile[buf][0][0] + (j * 256 + wave * 64) * 16);
        }
    };

    auto compute = [&](const char* Kt, const char* Vc) {
        bf16x8 paA[2], paB[2];
        __builtin_amdgcn_s_setprio(1);
#pragma unroll
        for (int st = 0; st < 4; ++st) {
            const int srow = st * 16 + lr;
            const int rs7 = lr & 7;
            bf16x8 kb0 = *(const bf16x8*)(Kt + srow * 128 + ((g ^ rs7) << 4));
            bf16x8 kb1 = *(const bf16x8*)(Kt + srow * 128 + (((4 + g) ^ rs7) << 4));
            f32x4 zA = f32x4{0.f,0.f,0.f,0.f}, zB = f32x4{0.f,0.f,0.f,0.f};
            zA = __builtin_amdgcn_mfma_f32_16x16x32_bf16(kb0, qa0, zA, 0, 0, 0);
            zA = __builtin_amdgcn_mfma_f32_16x16x32_bf16(kb1, qa1, zA, 0, 0, 0);
            zB = __builtin_amdgcn_mfma_f32_16x16x32_bf16(kb0, qb0, zB, 0, 0, 0);
            zB = __builtin_amdgcn_mfma_f32_16x16x32_bf16(kb1, qb1, zB, 0, 0, 0);
            float a0 = __builtin_amdgcn_exp2f(zA[0]);
            float a1 = __builtin_amdgcn_exp2f(zA[1]);
            float a2 = __builtin_amdgcn_exp2f(zA[2]);
            float a3 = __builtin_amdgcn_exp2f(zA[3]);
            float b0 = __builtin_amdgcn_exp2f(zB[0]);
            float b1 = __builtin_amdgcn_exp2f(zB[1]);
            float b2 = __builtin_amdgcn_exp2f(zB[2]);
            float b3 = __builtin_amdgcn_exp2f(zB[3]);
            const int kc = st >> 1, e0 = (st & 1) * 4;
            paA[kc][e0]     = (bf16_t)a0; paA[kc][e0 + 1] = (bf16_t)a1;
            paA[kc][e0 + 2] = (bf16_t)a2; paA[kc][e0 + 3] = (bf16_t)a3;
            paB[kc][e0]     = (bf16_t)b0; paB[kc][e0 + 1] = (bf16_t)b1;
            paB[kc][e0 + 2] = (bf16_t)b2; paB[kc][e0 + 3] = (bf16_t)b3;
            lpA += (a0 + a1) + (a2 + a3);
            lpB += (b0 + b1) + (b2 + b3);
        }
        __builtin_amdgcn_s_setprio(0);

        __builtin_amdgcn_s_setprio(1);
#pragma unroll
        for (int kc = 0; kc < 2; ++kc) {
#pragma unroll
            for (int n = 0; n < 4; ++n) {
                const int row = n * 16 + lr;
                bf16x8 vb = *(const bf16x8*)(Vc + row * 128 + (((kc * 4 + g) ^ (row & 7)) << 4));
                oA[n] = __builtin_amdgcn_mfma_f32_16x16x32_bf16(vb, paA[kc], oA[n], 0, 0, 0);
                oB[n] = __builtin_amdgcn_mfma_f32_16x16x32_bf16(vb, paB[kc], oB[n], 0, 0, 0);
            }
        }
        __builtin_amdgcn_s_setprio(0);
    };

    stage(0, 0);
    stage(64, 1);

    for (int step = 0; step < 32; ++step) {
        if (step + 2 < 32) stage((step + 2) * 64, (step + 2) & 3);
        if (step < 30)       asm volatile("s_waitcnt vmcnt(8)" ::: "memory");
        else if (step == 30) asm volatile("s_waitcnt vmcnt(4)" ::: "memory");
        else                 asm volatile("s_waitcnt vmcnt(0)" ::: "memory");
        __builtin_amdgcn_s_barrier();
        __builtin_amdgcn_sched_barrier(0);
        const int buf = step & 3;
        compute((const char*)&Ktile[buf][0][0], (const char*)&Vtile[buf][0][0]);
    }

    float lfA = lpA, lfB = lpB;
    lfA += __shfl_xor(lfA, 16, 64);
    lfA += __shfl_xor(lfA, 32, 64);
    lfB += __shfl_xor(lfB, 16, 64);
    lfB += __shfl_xor(lfB, 32, 64);
    float liA = 1.f / lfA, liB = 1.f / lfB;

    const int tA = q0 + lr, tB = q0 + 16 + lr;
#pragma unroll
    for (int n = 0; n < 4; ++n) {
        bf16x4 wA, wB;
#pragma unroll
        for (int r = 0; r < 4; ++r) {
            wA[r] = (bf16_t)(oA[n][r] * liA);
            wB[r] = (bf16_t)(oB[n][r] * liB);
        }
        *(bf16x4*)(ctx + ((size_t)(b * TSEQ + tA)) * DIM + h * HDIM + n * 16 + g * 4) = wA;
        *(bf16x4*)(ctx + ((size_t)(b * TSEQ + tB)) * DIM + h * HDIM + n * 16 + g * 4) = wB;
    }
}

// ---------------- launch ----------------
extern "C" void kernel_launch(void* const* d_in, const int* in_sizes, int n_in,
                              void* d_out, int out_size, void* d_ws, size_t ws_size,
                              hipStream_t stream) {
    const float* x    = (const float*)d_in[0];
    const float* Wqt  = (const float*)d_in[1];
    const float* Wkt  = (const float*)d_in[2];
    const float* Wqs  = (const float*)d_in[3];
    const float* Wks  = (const float*)d_in[4];
    const float* Wv   = (const float*)d_in[5];
    const float* Wout = (const float*)d_in[6];
    const float* bout = (const float*)d_in[7];
    const float* wsig = (const float*)d_in[8];
    (void)in_sizes; (void)n_in; (void)out_size; (void)ws_size;

    char* ws = (char*)d_ws;
    bf16_t* WqkvT = (bf16_t*)(ws + OFF_WQKVT);
    bf16_t* WoutT = (bf16_t*)(ws + OFF_WOUTT);
    bf16_t* Qb    = (bf16_t*)(ws + OFF_Q);
    bf16_t* Kb    = (bf16_t*)(ws + OFF_K);
    bf16_t* Vt    = (bf16_t*)(ws + OFF_VT);
    bf16_t* ctx   = (bf16_t*)(ws + OFF_CTX);
    bf16_t* Xb    = ctx;
    float*  out   = (float*)d_out;

    prep_all<<<3072, 256, 0, stream>>>(x, Wqt, Wkt, Wqs, Wks, Wv, Wout, Xb, WqkvT, WoutT);

    // x @ Wqkv -> Q, K, V; 2D XCD tile grouping (L2-fit working set), 768 blocks
    gemm1<<<768, 256, 0, stream>>>(Xb, WqkvT, Qb, Kb, Vt);

    // attention (round-18 best config): 512 blocks
    attn_kernel<<<512, 256, 0, stream>>>(Qb, Kb, Vt, ctx, wsig);

    // ctx @ Wout + bout -> d_out; 512 blocks (128x64 tiles) = 2/CU
    gemm_out<16, 2><<<512, 256, 0, stream>>>(ctx, WoutT, out, bout);
}